// Round 6
// baseline (244.382 us; speedup 1.0000x reference)
//
#include <hip/hip_runtime.h>
#include <hip/hip_bf16.h>

typedef __attribute__((ext_vector_type(8))) short short8;
typedef __attribute__((ext_vector_type(4))) float f32x4;
typedef __attribute__((ext_vector_type(2))) int i32x2;
typedef __attribute__((ext_vector_type(4))) int i32x4;

// float -> bf16 bits, round-to-nearest-even
__device__ inline unsigned short f2bs(float f) {
  union { float f; unsigned u; } v; v.f = f;
  unsigned r = v.u + 0x7fff + ((v.u >> 16) & 1);
  return (unsigned short)(r >> 16);
}

__device__ inline unsigned pkbf(float a, float b) {
  __hip_bfloat162 h = __float22bfloat162_rn(float2{a, b});
  union { __hip_bfloat162 h; unsigned u; } c; c.h = h;
  return c.u;
}

__device__ inline void gload16(const void* g, void* l) {
  __builtin_amdgcn_global_load_lds((const __attribute__((address_space(1))) void*)g,
                                   (__attribute__((address_space(3))) void*)l,
                                   16, 0, 0);
}

// ---------------- weight fp32 -> bf16 ----------------
__global__ void cvt_bf16(const float* __restrict__ in, unsigned short* __restrict__ out, int n4) {
  int i = blockIdx.x * blockDim.x + threadIdx.x;
  if (i >= n4) return;
  float4 v = ((const float4*)in)[i];
  ushort4 o;
  o.x = f2bs(v.x); o.y = f2bs(v.y); o.z = f2bs(v.z); o.w = f2bs(v.w);
  ((ushort4*)out)[i] = o;
}

// ---------------- LayerNorm: fp32 in -> bf16 out ----------------
__global__ __launch_bounds__(256)
void ln_kernel(const float* __restrict__ x, const float* __restrict__ w,
               const float* __restrict__ bsh, unsigned short* __restrict__ out)
{
  const int row = blockIdx.x;
  const float* xr = x + (size_t)row * 768;
  float v[3];
  float s = 0.f, sq = 0.f;
#pragma unroll
  for (int i = 0; i < 3; ++i) {
    v[i] = xr[threadIdx.x + i * 256];
    s += v[i]; sq += v[i] * v[i];
  }
#pragma unroll
  for (int d = 1; d < 64; d <<= 1) {
    s  += __shfl_xor(s, d, 64);
    sq += __shfl_xor(sq, d, 64);
  }
  __shared__ float ss[4], ssq[4];
  const int wv = threadIdx.x >> 6;
  if ((threadIdx.x & 63) == 0) { ss[wv] = s; ssq[wv] = sq; }
  __syncthreads();
  s  = ss[0] + ss[1] + ss[2] + ss[3];
  sq = ssq[0] + ssq[1] + ssq[2] + ssq[3];
  const float mu = s * (1.0f / 768.0f);
  const float var = sq * (1.0f / 768.0f) - mu * mu;
  const float rstd = rsqrtf(var + 1e-5f);
#pragma unroll
  for (int i = 0; i < 3; ++i) {
    const int c = threadIdx.x + i * 256;
    out[(size_t)row * 768 + c] = f2bs((v[i] - mu) * rstd * w[c] + bsh[c]);
  }
}

// ---------------- NT GEMM: C[m,n] = sum_k A[m,k]*Bw[n,k], bf16 in, f32 acc ----------------
// Double-buffered LDS + counted vmcnt (prefetch never drained in-loop).
// EPI 0: qkv scatter -> Q,K bf16 [B,H,N,D] (Q pre-scaled by 8), V bf16 [B,H,D,N]
// EPI 1/3: + bias + resid -> f32 out
// EPI 2: + bias, GELU(exact) -> bf16 out
template<int EPI>
__global__ __launch_bounds__(256, 2)
void gemm_nt(const unsigned short* __restrict__ A,
             const unsigned short* __restrict__ Bw,
             const float* __restrict__ bias,
             const float* __restrict__ resid,
             void* __restrict__ out0, void* __restrict__ out1, void* __restrict__ out2,
             int M, int N, int K)
{
  __shared__ __align__(16) unsigned short As[2][128 * 32];
  __shared__ __align__(16) unsigned short Bs[2][128 * 32];
  const int tid = threadIdx.x;
  const int lane = tid & 63;
  const int w = tid >> 6;
  const int wr = w >> 1, wc = w & 1;
  const int l15 = lane & 15, g = lane >> 4;
  const int m0 = blockIdx.y * 128;
  const int n0 = blockIdx.x * 128;

  f32x4 acc[4][4];
#pragma unroll
  for (int m = 0; m < 4; ++m)
#pragma unroll
    for (int n = 0; n < 4; ++n)
      acc[m][n] = (f32x4){0.f, 0.f, 0.f, 0.f};

  auto stage = [&](int buf, int k0) {
#pragma unroll
    for (int i = 0; i < 2; ++i) {
      const int f = tid + i * 256;
      const int row = f >> 2, c8 = f & 3;
      const int sc = c8 ^ (row & 3);
      gload16(A  + (size_t)(m0 + row) * K + k0 + sc * 8, (char*)&As[buf][0] + f * 16);
      gload16(Bw + (size_t)(n0 + row) * K + k0 + sc * 8, (char*)&Bs[buf][0] + f * 16);
    }
  };

  const int NT = K >> 5;
  stage(0, 0);
  int cur = 0;

  for (int t = 0; t < NT; ++t) {
    if (t + 1 < NT) {
      stage(cur ^ 1, (t + 1) * 32);
      asm volatile("s_waitcnt vmcnt(4)" ::: "memory");
    } else {
      asm volatile("s_waitcnt vmcnt(0)" ::: "memory");
    }
    __builtin_amdgcn_s_barrier();
    asm volatile("" ::: "memory");

    short8 af[4], bfr[4];
#pragma unroll
    for (int m = 0; m < 4; ++m) {
      const int r = wr * 64 + m * 16 + l15;
      af[m] = *(const short8*)((const char*)&As[cur][0] + ((size_t)r * 32 + (g ^ (r & 3)) * 8) * 2);
    }
#pragma unroll
    for (int n = 0; n < 4; ++n) {
      const int r = wc * 64 + n * 16 + l15;
      bfr[n] = *(const short8*)((const char*)&Bs[cur][0] + ((size_t)r * 32 + (g ^ (r & 3)) * 8) * 2);
    }
    __builtin_amdgcn_s_setprio(1);
#pragma unroll
    for (int m = 0; m < 4; ++m)
#pragma unroll
      for (int n = 0; n < 4; ++n)
        acc[m][n] = __builtin_amdgcn_mfma_f32_16x16x32_bf16(af[m], bfr[n], acc[m][n], 0, 0, 0);
    __builtin_amdgcn_s_setprio(0);

    asm volatile("" ::: "memory");
    __builtin_amdgcn_s_barrier();
    cur ^= 1;
  }

  // epilogue: C/D layout col = lane&15, row = (lane>>4)*4 + j
#pragma unroll
  for (int m = 0; m < 4; ++m) {
    const int gmBase = m0 + wr * 64 + m * 16 + g * 4;
#pragma unroll
    for (int n = 0; n < 4; ++n) {
      const int gn = n0 + wc * 64 + n * 16 + l15;
      const float bval = bias[gn];
      float vj[4];
#pragma unroll
      for (int j = 0; j < 4; ++j) vj[j] = acc[m][n][j] + bval;
      if (EPI == 0) {
        const int three = gn / 768;
        const int hh = (gn % 768) >> 6;
        const int d = gn & 63;
        const int bb = gmBase >> 11, t = gmBase & 2047;
        if (three == 2) {
          // V transposed: [b,h,d,2048], 4 consecutive tokens -> one 8B store
          ushort4 pk;
          pk.x = f2bs(vj[0]); pk.y = f2bs(vj[1]); pk.z = f2bs(vj[2]); pk.w = f2bs(vj[3]);
          *(ushort4*)((unsigned short*)out2 + (((size_t)bb * 12 + hh) * 64 + d) * 2048 + t) = pk;
        } else {
          unsigned short* dst = (three == 0) ? (unsigned short*)out0 : (unsigned short*)out1;
#pragma unroll
          for (int j = 0; j < 4; ++j) {
            float v = vj[j];
            if (three == 0) v *= 8.0f;   // fold attention scale into Q
            dst[(((size_t)bb * 12 + hh) * 2048 + (t + j)) * 64 + d] = f2bs(v);
          }
        }
      } else if (EPI == 1 || EPI == 3) {
#pragma unroll
        for (int j = 0; j < 4; ++j) {
          const int gm = gmBase + j;
          ((float*)out0)[(size_t)gm * N + gn] = vj[j] + resid[(size_t)gm * N + gn];
        }
      } else {
#pragma unroll
        for (int j = 0; j < 4; ++j) {
          const int gm = gmBase + j;
          const float ge = 0.5f * vj[j] * (1.0f + erff(vj[j] * 0.70710678f));
          ((unsigned short*)out0)[(size_t)gm * N + gn] = f2bs(ge);
        }
      }
    }
  }
}

// ---------------- Flash attention fwd v4 ----------------
// v3 + counted-vmcnt double-buffer (prefetch survives the barrier).
// Swapped QK^T (lane-local P rows), frag-ordered K staging, V^T global layout
// staged into XOR-swizzled [64d][64k] LDS, PV B-frags via two 8B LDS loads.
// grid (N/64, B*H), 256 threads (4 waves), each wave owns 16 q-rows.
__global__ __launch_bounds__(256, 2)
void attn_fwd(const unsigned short* __restrict__ Q,
              const unsigned short* __restrict__ K,
              const unsigned short* __restrict__ Vt,
              unsigned short* __restrict__ O)
{
  __shared__ __align__(1024) unsigned short Ks[2][8 * 512];  // frag f=n*2+kc, lane*16B
  __shared__ __align__(1024) unsigned short Vs[2][4096];     // [64d][64k], 16B-block swizzle t^=(d&7)
  const int tid = threadIdx.x, lane = tid & 63, w = tid >> 6;
  const int l15 = lane & 15, g = lane >> 4;
  const int bh = blockIdx.y, b = bh / 12, h = bh % 12;
  const int q0 = blockIdx.x * 64;
  const unsigned short* Qb = Q  + (size_t)bh * 2048 * 64;
  const unsigned short* Kb = K  + (size_t)bh * 2048 * 64;
  const unsigned short* Vb = Vt + (size_t)bh * 64 * 2048;

  const int qr = q0 + w * 16 + l15;
  short8 qf[2];
  qf[0] = *(const short8*)(Qb + (size_t)qr * 64 + g * 8);
  qf[1] = *(const short8*)(Qb + (size_t)qr * 64 + 32 + g * 8);

  float m_run = -1e30f, l_run = 0.f;
  f32x4 o_acc[4];
#pragma unroll
  for (int dc = 0; dc < 4; ++dc) o_acc[dc] = (f32x4){0.f, 0.f, 0.f, 0.f};

  const int vtok = ((lane & 7) ^ (lane >> 3)) * 8;  // pre-swizzled source token offset

  auto stage = [&](int buf, int kb) {
#pragma unroll
    for (int i = 0; i < 2; ++i) {
      const int f = w * 2 + i;
      const int n = f >> 1, kc = f & 1;
      gload16(Kb + (size_t)(kb + n * 16 + l15) * 64 + kc * 32 + g * 8,
              (char*)&Ks[buf][0] + f * 1024);
    }
#pragma unroll
    for (int i = 0; i < 2; ++i) {
      const int c = w * 2 + i;
      const int d = c * 8 + (lane >> 3);
      gload16(Vb + (size_t)d * 2048 + kb + vtok,
              (char*)&Vs[buf][0] + c * 1024);
    }
  };

  stage(0, 0);
  __syncthreads();   // drain prologue (qf + tile0) once
  int cur = 0;

  for (int t = 0; t < 32; ++t) {
    if (t < 31) {
      stage(cur ^ 1, (t + 1) * 64);
      asm volatile("s_waitcnt vmcnt(4)" ::: "memory");
    } else {
      asm volatile("s_waitcnt vmcnt(0)" ::: "memory");
    }
    __builtin_amdgcn_s_barrier();
    asm volatile("" ::: "memory");

    // --- S^T = K · Q^T : lane holds S[q=l15][key = n*16 + 4g + j] ---
    f32x4 s2[4];
#pragma unroll
    for (int n = 0; n < 4; ++n) s2[n] = (f32x4){0.f, 0.f, 0.f, 0.f};
    __builtin_amdgcn_s_setprio(1);
#pragma unroll
    for (int n = 0; n < 4; ++n) {
      short8 kf0 = *(const short8*)(&Ks[cur][(n * 2 + 0) * 512 + lane * 8]);
      short8 kf1 = *(const short8*)(&Ks[cur][(n * 2 + 1) * 512 + lane * 8]);
      s2[n] = __builtin_amdgcn_mfma_f32_16x16x32_bf16(kf0, qf[0], s2[n], 0, 0, 0);
      s2[n] = __builtin_amdgcn_mfma_f32_16x16x32_bf16(kf1, qf[1], s2[n], 0, 0, 0);
    }
    __builtin_amdgcn_s_setprio(0);

    // --- online softmax, fully in-register (q = l15 per lane) ---
    float mx = s2[0][0];
#pragma unroll
    for (int n = 0; n < 4; ++n)
#pragma unroll
      for (int j = 0; j < 4; ++j) mx = fmaxf(mx, s2[n][j]);
    mx = fmaxf(mx, __shfl_xor(mx, 16, 64));
    mx = fmaxf(mx, __shfl_xor(mx, 32, 64));
    if (__any(mx > m_run)) {
      const float mn = fmaxf(m_run, mx);
      const float alpha = __expf(m_run - mn);
      m_run = mn;
      l_run *= alpha;
#pragma unroll
      for (int j = 0; j < 4; ++j) {
        const float aB = __shfl(alpha, (lane & 48) | (g * 4 + j), 64);
#pragma unroll
        for (int dc = 0; dc < 4; ++dc) o_acc[dc][j] *= aB;
      }
    }
    float e[4][4];
    float rs = 0.f;
#pragma unroll
    for (int n = 0; n < 4; ++n)
#pragma unroll
      for (int j = 0; j < 4; ++j) {
        e[n][j] = __expf(s2[n][j] - m_run);
        rs += e[n][j];
      }
    rs += __shfl_xor(rs, 16, 64);
    rs += __shfl_xor(rs, 32, 64);
    l_run += rs;

    // --- pack P fragments: slot s=g*8+i -> key (2kc + (i>=4))*16 + 4g + (i&3) ---
    unsigned pw[2][4];
#pragma unroll
    for (int kc = 0; kc < 2; ++kc) {
      pw[kc][0] = pkbf(e[2 * kc][0],     e[2 * kc][1]);
      pw[kc][1] = pkbf(e[2 * kc][2],     e[2 * kc][3]);
      pw[kc][2] = pkbf(e[2 * kc + 1][0], e[2 * kc + 1][1]);
      pw[kc][3] = pkbf(e[2 * kc + 1][2], e[2 * kc + 1][3]);
    }

    // --- O += P · V : V-frags from swizzled [d][k] LDS, two 8B loads each ---
    const char* vsb = (const char*)&Vs[cur][0];
    const unsigned sw = (unsigned)(l15 & 7) << 4;
#pragma unroll
    for (int kc = 0; kc < 2; ++kc) {
      i32x4 pt; pt.x = (int)pw[kc][0]; pt.y = (int)pw[kc][1]; pt.z = (int)pw[kc][2]; pt.w = (int)pw[kc][3];
      short8 pf = *(short8*)&pt;
      __builtin_amdgcn_s_setprio(1);
#pragma unroll
      for (int dc = 0; dc < 4; ++dc) {
        const unsigned row = (unsigned)(dc * 16 + l15) * 128;
        i32x2 ra  = *(const i32x2*)(vsb + row + (((unsigned)(kc * 64 + g * 8)) ^ sw));
        i32x2 rb2 = *(const i32x2*)(vsb + row + (((unsigned)(kc * 64 + 32 + g * 8)) ^ sw));
        i32x4 vt4; vt4.x = ra.x; vt4.y = ra.y; vt4.z = rb2.x; vt4.w = rb2.y;
        short8 vf = *(short8*)&vt4;
        o_acc[dc] = __builtin_amdgcn_mfma_f32_16x16x32_bf16(pf, vf, o_acc[dc], 0, 0, 0);
      }
      __builtin_amdgcn_s_setprio(0);
    }

    asm volatile("" ::: "memory");
    __builtin_amdgcn_s_barrier();   // release buffers; prefetch stays in flight
    cur ^= 1;
  }

  // --- epilogue: o_acc[dc][j] = O[q = q0+w*16+g*4+j][d = dc*16+l15] ---
#pragma unroll
  for (int j = 0; j < 4; ++j) {
    const float lB = __shfl(l_run, (lane & 48) | (g * 4 + j), 64);
    const float inv = 1.0f / lB;
    const int qrow = q0 + w * 16 + g * 4 + j;
#pragma unroll
    for (int dc = 0; dc < 4; ++dc) {
      O[((size_t)b * 2048 + qrow) * 768 + h * 64 + dc * 16 + l15] = f2bs(o_acc[dc][j] * inv);
    }
  }
}

extern "C" void kernel_launch(void* const* d_in, const int* in_sizes, int n_in,
                              void* d_out, int out_size, void* d_ws, size_t ws_size,
                              hipStream_t stream)
{
  const float* x      = (const float*)d_in[0];
  const float* ln1_w  = (const float*)d_in[1];
  const float* ln1_b  = (const float*)d_in[2];
  const float* qkv_w  = (const float*)d_in[3];
  const float* qkv_b  = (const float*)d_in[4];
  const float* proj_w = (const float*)d_in[5];
  const float* proj_b = (const float*)d_in[6];
  const float* ln2_w  = (const float*)d_in[7];
  const float* ln2_b  = (const float*)d_in[8];
  const float* fc1_w  = (const float*)d_in[9];
  const float* fc1_b  = (const float*)d_in[10];
  const float* fc2_w  = (const float*)d_in[11];
  const float* fc2_b  = (const float*)d_in[12];

  char* base = (char*)d_ws;
  size_t off = 0;
  auto take = [&](size_t bytes) {
    void* r = base + off;
    off = (off + bytes + 255) & ~(size_t)255;
    return r;
  };
  unsigned short* wq = (unsigned short*)take(2304ull * 768 * 2);
  unsigned short* wp = (unsigned short*)take(768ull * 768 * 2);
  unsigned short* w1 = (unsigned short*)take(3072ull * 768 * 2);
  unsigned short* w2 = (unsigned short*)take(768ull * 3072 * 2);
  unsigned short* h  = (unsigned short*)take(4096ull * 768 * 2);   // LN out / attn O / LN2 out
  float* x2          = (float*)take(4096ull * 768 * 4);            // post-attn residual stream
  char* big          = (char*)take(4096ull * 3072 * 2);            // Q,K,V then FC1 act
  unsigned short* Qb = (unsigned short*)big;
  unsigned short* Kb = (unsigned short*)(big + 4096ull * 768 * 2);
  unsigned short* Vb = (unsigned short*)(big + 2ull * 4096 * 768 * 2);  // [b,h,d,2048]
  unsigned short* a2 = (unsigned short*)big;

  int n4;
  n4 = 2304 * 768 / 4; cvt_bf16<<<(n4 + 255) / 256, 256, 0, stream>>>(qkv_w, wq, n4);
  n4 = 768 * 768 / 4;  cvt_bf16<<<(n4 + 255) / 256, 256, 0, stream>>>(proj_w, wp, n4);
  n4 = 3072 * 768 / 4; cvt_bf16<<<(n4 + 255) / 256, 256, 0, stream>>>(fc1_w, w1, n4);
  n4 = 768 * 3072 / 4; cvt_bf16<<<(n4 + 255) / 256, 256, 0, stream>>>(fc2_w, w2, n4);

  ln_kernel<<<4096, 256, 0, stream>>>(x, ln1_w, ln1_b, h);
  gemm_nt<0><<<dim3(18, 32), 256, 0, stream>>>(h, wq, qkv_b, nullptr, Qb, Kb, Vb, 4096, 2304, 768);
  attn_fwd<<<dim3(32, 24), 256, 0, stream>>>(Qb, Kb, Vb, h);
  gemm_nt<1><<<dim3(6, 32), 256, 0, stream>>>(h, wp, proj_b, x, x2, nullptr, nullptr, 4096, 768, 768);
  ln_kernel<<<4096, 256, 0, stream>>>(x2, ln2_w, ln2_b, h);
  gemm_nt<2><<<dim3(24, 32), 256, 0, stream>>>(h, w1, fc1_b, nullptr, a2, nullptr, nullptr, 4096, 3072, 768);
  gemm_nt<3><<<dim3(6, 32), 256, 0, stream>>>(a2, w2, fc2_b, x2, d_out, nullptr, nullptr, 4096, 768, 3072);
}

// Round 7
// 235.240 us; speedup vs baseline: 1.0389x; 1.0389x over previous
//
#include <hip/hip_runtime.h>
#include <hip/hip_bf16.h>

typedef __attribute__((ext_vector_type(8))) short short8;
typedef __attribute__((ext_vector_type(4))) float f32x4;
typedef __attribute__((ext_vector_type(2))) int i32x2;
typedef __attribute__((ext_vector_type(4))) int i32x4;

// float -> bf16 bits, round-to-nearest-even
__device__ inline unsigned short f2bs(float f) {
  union { float f; unsigned u; } v; v.f = f;
  unsigned r = v.u + 0x7fff + ((v.u >> 16) & 1);
  return (unsigned short)(r >> 16);
}

__device__ inline unsigned pkbf(float a, float b) {
  __hip_bfloat162 h = __float22bfloat162_rn(float2{a, b});
  union { __hip_bfloat162 h; unsigned u; } c; c.h = h;
  return c.u;
}

__device__ inline void gload16(const void* g, void* l) {
  __builtin_amdgcn_global_load_lds((const __attribute__((address_space(1))) void*)g,
                                   (__attribute__((address_space(3))) void*)l,
                                   16, 0, 0);
}

// ---------------- weight fp32 -> bf16 ----------------
__global__ void cvt_bf16(const float* __restrict__ in, unsigned short* __restrict__ out, int n4) {
  int i = blockIdx.x * blockDim.x + threadIdx.x;
  if (i >= n4) return;
  float4 v = ((const float4*)in)[i];
  ushort4 o;
  o.x = f2bs(v.x); o.y = f2bs(v.y); o.z = f2bs(v.z); o.w = f2bs(v.w);
  ((ushort4*)out)[i] = o;
}

// ---------------- LayerNorm: fp32 in -> bf16 out ----------------
__global__ __launch_bounds__(256)
void ln_kernel(const float* __restrict__ x, const float* __restrict__ w,
               const float* __restrict__ bsh, unsigned short* __restrict__ out)
{
  const int row = blockIdx.x;
  const float* xr = x + (size_t)row * 768;
  float v[3];
  float s = 0.f, sq = 0.f;
#pragma unroll
  for (int i = 0; i < 3; ++i) {
    v[i] = xr[threadIdx.x + i * 256];
    s += v[i]; sq += v[i] * v[i];
  }
#pragma unroll
  for (int d = 1; d < 64; d <<= 1) {
    s  += __shfl_xor(s, d, 64);
    sq += __shfl_xor(sq, d, 64);
  }
  __shared__ float ss[4], ssq[4];
  const int wv = threadIdx.x >> 6;
  if ((threadIdx.x & 63) == 0) { ss[wv] = s; ssq[wv] = sq; }
  __syncthreads();
  s  = ss[0] + ss[1] + ss[2] + ss[3];
  sq = ssq[0] + ssq[1] + ssq[2] + ssq[3];
  const float mu = s * (1.0f / 768.0f);
  const float var = sq * (1.0f / 768.0f) - mu * mu;
  const float rstd = rsqrtf(var + 1e-5f);
#pragma unroll
  for (int i = 0; i < 3; ++i) {
    const int c = threadIdx.x + i * 256;
    out[(size_t)row * 768 + c] = f2bs((v[i] - mu) * rstd * w[c] + bsh[c]);
  }
}

// ---------------- NT GEMM: C[m,n] = sum_k A[m,k]*Bw[n,k], bf16 in, f32 acc ----------------
// XCD-swizzled blockIdx (consecutive n-tiles of one m-panel share an XCD's L2),
// triple-buffered LDS, depth-2 prefetch with counted vmcnt.
// EPI 0: qkv scatter -> Q,K bf16 [B,H,N,D] (Q pre-scaled by 8), V bf16 [B,H,D,N]
// EPI 1/3: + bias + resid -> f32 out
// EPI 2: + bias, GELU(exact) -> bf16 out
template<int EPI>
__global__ __launch_bounds__(256, 2)
void gemm_nt(const unsigned short* __restrict__ A,
             const unsigned short* __restrict__ Bw,
             const float* __restrict__ bias,
             const float* __restrict__ resid,
             void* __restrict__ out0, void* __restrict__ out1, void* __restrict__ out2,
             int M, int N, int K)
{
  __shared__ __align__(16) unsigned short As[3][128 * 32];
  __shared__ __align__(16) unsigned short Bs[3][128 * 32];
  const int tid = threadIdx.x;
  const int lane = tid & 63;
  const int w = tid >> 6;
  const int wr = w >> 1, wc = w & 1;
  const int l15 = lane & 15, g = lane >> 4;

  // bijective XCD swizzle (all grids divisible by 8): same-XCD blocks walk n fastest
  const int nwg = gridDim.x * gridDim.y;
  const int hw = blockIdx.y * gridDim.x + blockIdx.x;
  const int virt = (hw & 7) * (nwg >> 3) + (hw >> 3);
  const int m0 = (virt / gridDim.x) * 128;
  const int n0 = (virt % gridDim.x) * 128;

  f32x4 acc[4][4];
#pragma unroll
  for (int m = 0; m < 4; ++m)
#pragma unroll
    for (int n = 0; n < 4; ++n)
      acc[m][n] = (f32x4){0.f, 0.f, 0.f, 0.f};

  auto stage = [&](int buf, int k0) {
#pragma unroll
    for (int i = 0; i < 2; ++i) {
      const int f = tid + i * 256;
      const int row = f >> 2, c8 = f & 3;
      const int sc = c8 ^ (row & 3);
      gload16(A  + (size_t)(m0 + row) * K + k0 + sc * 8, (char*)&As[buf][0] + f * 16);
      gload16(Bw + (size_t)(n0 + row) * K + k0 + sc * 8, (char*)&Bs[buf][0] + f * 16);
    }
  };

  const int NT = K >> 5;
  stage(0, 0);
  stage(1, 32);

  for (int t = 0; t < NT; ++t) {
    const int buf = t % 3;
    if (t + 2 < NT) {
      stage((t + 2) % 3, (t + 2) * 32);
      asm volatile("s_waitcnt vmcnt(8)" ::: "memory");
    } else if (t + 1 < NT) {
      asm volatile("s_waitcnt vmcnt(4)" ::: "memory");
    } else {
      asm volatile("s_waitcnt vmcnt(0)" ::: "memory");
    }
    __builtin_amdgcn_s_barrier();
    asm volatile("" ::: "memory");

    short8 af[4], bfr[4];
#pragma unroll
    for (int m = 0; m < 4; ++m) {
      const int r = wr * 64 + m * 16 + l15;
      af[m] = *(const short8*)((const char*)&As[buf][0] + ((size_t)r * 32 + (g ^ (r & 3)) * 8) * 2);
    }
#pragma unroll
    for (int n = 0; n < 4; ++n) {
      const int r = wc * 64 + n * 16 + l15;
      bfr[n] = *(const short8*)((const char*)&Bs[buf][0] + ((size_t)r * 32 + (g ^ (r & 3)) * 8) * 2);
    }
    __builtin_amdgcn_s_setprio(1);
#pragma unroll
    for (int m = 0; m < 4; ++m)
#pragma unroll
      for (int n = 0; n < 4; ++n)
        acc[m][n] = __builtin_amdgcn_mfma_f32_16x16x32_bf16(af[m], bfr[n], acc[m][n], 0, 0, 0);
    __builtin_amdgcn_s_setprio(0);

    asm volatile("" ::: "memory");
    __builtin_amdgcn_s_barrier();
  }

  // epilogue: C/D layout col = lane&15, row = (lane>>4)*4 + j
#pragma unroll
  for (int m = 0; m < 4; ++m) {
    const int gmBase = m0 + wr * 64 + m * 16 + g * 4;
#pragma unroll
    for (int n = 0; n < 4; ++n) {
      const int gn = n0 + wc * 64 + n * 16 + l15;
      const float bval = bias[gn];
      float vj[4];
#pragma unroll
      for (int j = 0; j < 4; ++j) vj[j] = acc[m][n][j] + bval;
      if (EPI == 0) {
        const int three = gn / 768;
        const int hh = (gn % 768) >> 6;
        const int d = gn & 63;
        const int bb = gmBase >> 11, t = gmBase & 2047;
        if (three == 2) {
          // V transposed: [b,h,d,2048], 4 consecutive tokens -> one 8B store
          ushort4 pk;
          pk.x = f2bs(vj[0]); pk.y = f2bs(vj[1]); pk.z = f2bs(vj[2]); pk.w = f2bs(vj[3]);
          *(ushort4*)((unsigned short*)out2 + (((size_t)bb * 12 + hh) * 64 + d) * 2048 + t) = pk;
        } else {
          unsigned short* dst = (three == 0) ? (unsigned short*)out0 : (unsigned short*)out1;
#pragma unroll
          for (int j = 0; j < 4; ++j) {
            float v = vj[j];
            if (three == 0) v *= 8.0f;   // fold attention scale into Q
            dst[(((size_t)bb * 12 + hh) * 2048 + (t + j)) * 64 + d] = f2bs(v);
          }
        }
      } else if (EPI == 1 || EPI == 3) {
#pragma unroll
        for (int j = 0; j < 4; ++j) {
          const int gm = gmBase + j;
          ((float*)out0)[(size_t)gm * N + gn] = vj[j] + resid[(size_t)gm * N + gn];
        }
      } else {
#pragma unroll
        for (int j = 0; j < 4; ++j) {
          const int gm = gmBase + j;
          const float ge = 0.5f * vj[j] * (1.0f + erff(vj[j] * 0.70710678f));
          ((unsigned short*)out0)[(size_t)gm * N + gn] = f2bs(ge);
        }
      }
    }
  }
}

// ---------------- Flash attention fwd v5 ----------------
// v4 + XCD swizzle (32 q-blocks of one (b,h) share an XCD -> K/V L2-resident).
// Swapped QK^T (lane-local P rows), frag-ordered K staging, V^T global layout
// staged into XOR-swizzled [64d][64k] LDS, PV B-frags via two 8B LDS loads.
// grid 768 linear, 256 threads (4 waves), each wave owns 16 q-rows.
__global__ __launch_bounds__(256, 2)
void attn_fwd(const unsigned short* __restrict__ Q,
              const unsigned short* __restrict__ K,
              const unsigned short* __restrict__ Vt,
              unsigned short* __restrict__ O)
{
  __shared__ __align__(1024) unsigned short Ks[2][8 * 512];  // frag f=n*2+kc, lane*16B
  __shared__ __align__(1024) unsigned short Vs[2][4096];     // [64d][64k], 16B-block swizzle t^=(d&7)
  const int tid = threadIdx.x, lane = tid & 63, w = tid >> 6;
  const int l15 = lane & 15, g = lane >> 4;

  // bijective XCD swizzle: nwg=768; each XCD gets 3 bh-groups x 32 q-blocks
  const int hw = blockIdx.y * gridDim.x + blockIdx.x;
  const int virt = (hw & 7) * 96 + (hw >> 3);
  const int qblk = virt & 31;
  const int bh = virt >> 5;
  const int b = bh / 12, h = bh % 12;
  const int q0 = qblk * 64;
  const unsigned short* Qb = Q  + (size_t)bh * 2048 * 64;
  const unsigned short* Kb = K  + (size_t)bh * 2048 * 64;
  const unsigned short* Vb = Vt + (size_t)bh * 64 * 2048;

  const int qr = q0 + w * 16 + l15;
  short8 qf[2];
  qf[0] = *(const short8*)(Qb + (size_t)qr * 64 + g * 8);
  qf[1] = *(const short8*)(Qb + (size_t)qr * 64 + 32 + g * 8);

  float m_run = -1e30f, l_run = 0.f;
  f32x4 o_acc[4];
#pragma unroll
  for (int dc = 0; dc < 4; ++dc) o_acc[dc] = (f32x4){0.f, 0.f, 0.f, 0.f};

  const int vtok = ((lane & 7) ^ (lane >> 3)) * 8;  // pre-swizzled source token offset

  auto stage = [&](int buf, int kb) {
#pragma unroll
    for (int i = 0; i < 2; ++i) {
      const int f = w * 2 + i;
      const int n = f >> 1, kc = f & 1;
      gload16(Kb + (size_t)(kb + n * 16 + l15) * 64 + kc * 32 + g * 8,
              (char*)&Ks[buf][0] + f * 1024);
    }
#pragma unroll
    for (int i = 0; i < 2; ++i) {
      const int c = w * 2 + i;
      const int d = c * 8 + (lane >> 3);
      gload16(Vb + (size_t)d * 2048 + kb + vtok,
              (char*)&Vs[buf][0] + c * 1024);
    }
  };

  stage(0, 0);
  __syncthreads();   // drain prologue (qf + tile0) once
  int cur = 0;

  for (int t = 0; t < 32; ++t) {
    if (t < 31) {
      stage(cur ^ 1, (t + 1) * 64);
      asm volatile("s_waitcnt vmcnt(4)" ::: "memory");
    } else {
      asm volatile("s_waitcnt vmcnt(0)" ::: "memory");
    }
    __builtin_amdgcn_s_barrier();
    asm volatile("" ::: "memory");

    // --- S^T = K · Q^T : lane holds S[q=l15][key = n*16 + 4g + j] ---
    f32x4 s2[4];
#pragma unroll
    for (int n = 0; n < 4; ++n) s2[n] = (f32x4){0.f, 0.f, 0.f, 0.f};
    __builtin_amdgcn_s_setprio(1);
#pragma unroll
    for (int n = 0; n < 4; ++n) {
      short8 kf0 = *(const short8*)(&Ks[cur][(n * 2 + 0) * 512 + lane * 8]);
      short8 kf1 = *(const short8*)(&Ks[cur][(n * 2 + 1) * 512 + lane * 8]);
      s2[n] = __builtin_amdgcn_mfma_f32_16x16x32_bf16(kf0, qf[0], s2[n], 0, 0, 0);
      s2[n] = __builtin_amdgcn_mfma_f32_16x16x32_bf16(kf1, qf[1], s2[n], 0, 0, 0);
    }
    __builtin_amdgcn_s_setprio(0);

    // --- online softmax, fully in-register (q = l15 per lane) ---
    float mx = s2[0][0];
#pragma unroll
    for (int n = 0; n < 4; ++n)
#pragma unroll
      for (int j = 0; j < 4; ++j) mx = fmaxf(mx, s2[n][j]);
    mx = fmaxf(mx, __shfl_xor(mx, 16, 64));
    mx = fmaxf(mx, __shfl_xor(mx, 32, 64));
    if (__any(mx > m_run)) {
      const float mn = fmaxf(m_run, mx);
      const float alpha = __expf(m_run - mn);
      m_run = mn;
      l_run *= alpha;
#pragma unroll
      for (int j = 0; j < 4; ++j) {
        const float aB = __shfl(alpha, (lane & 48) | (g * 4 + j), 64);
#pragma unroll
        for (int dc = 0; dc < 4; ++dc) o_acc[dc][j] *= aB;
      }
    }
    float e[4][4];
    float rs = 0.f;
#pragma unroll
    for (int n = 0; n < 4; ++n)
#pragma unroll
      for (int j = 0; j < 4; ++j) {
        e[n][j] = __expf(s2[n][j] - m_run);
        rs += e[n][j];
      }
    rs += __shfl_xor(rs, 16, 64);
    rs += __shfl_xor(rs, 32, 64);
    l_run += rs;

    // --- pack P fragments: slot s=g*8+i -> key (2kc + (i>=4))*16 + 4g + (i&3) ---
    unsigned pw[2][4];
#pragma unroll
    for (int kc = 0; kc < 2; ++kc) {
      pw[kc][0] = pkbf(e[2 * kc][0],     e[2 * kc][1]);
      pw[kc][1] = pkbf(e[2 * kc][2],     e[2 * kc][3]);
      pw[kc][2] = pkbf(e[2 * kc + 1][0], e[2 * kc + 1][1]);
      pw[kc][3] = pkbf(e[2 * kc + 1][2], e[2 * kc + 1][3]);
    }

    // --- O += P · V : V-frags from swizzled [d][k] LDS, two 8B loads each ---
    const char* vsb = (const char*)&Vs[cur][0];
    const unsigned sw = (unsigned)(l15 & 7) << 4;
#pragma unroll
    for (int kc = 0; kc < 2; ++kc) {
      i32x4 pt; pt.x = (int)pw[kc][0]; pt.y = (int)pw[kc][1]; pt.z = (int)pw[kc][2]; pt.w = (int)pw[kc][3];
      short8 pf = *(short8*)&pt;
      __builtin_amdgcn_s_setprio(1);
#pragma unroll
      for (int dc = 0; dc < 4; ++dc) {
        const unsigned row = (unsigned)(dc * 16 + l15) * 128;
        i32x2 ra  = *(const i32x2*)(vsb + row + (((unsigned)(kc * 64 + g * 8)) ^ sw));
        i32x2 rb2 = *(const i32x2*)(vsb + row + (((unsigned)(kc * 64 + 32 + g * 8)) ^ sw));
        i32x4 vt4; vt4.x = ra.x; vt4.y = ra.y; vt4.z = rb2.x; vt4.w = rb2.y;
        short8 vf = *(short8*)&vt4;
        o_acc[dc] = __builtin_amdgcn_mfma_f32_16x16x32_bf16(pf, vf, o_acc[dc], 0, 0, 0);
      }
      __builtin_amdgcn_s_setprio(0);
    }

    asm volatile("" ::: "memory");
    __builtin_amdgcn_s_barrier();   // release buffers; prefetch stays in flight
    cur ^= 1;
  }

  // --- epilogue: o_acc[dc][j] = O[q = q0+w*16+g*4+j][d = dc*16+l15] ---
#pragma unroll
  for (int j = 0; j < 4; ++j) {
    const float lB = __shfl(l_run, (lane & 48) | (g * 4 + j), 64);
    const float inv = 1.0f / lB;
    const int qrow = q0 + w * 16 + g * 4 + j;
#pragma unroll
    for (int dc = 0; dc < 4; ++dc) {
      O[((size_t)b * 2048 + qrow) * 768 + h * 64 + dc * 16 + l15] = f2bs(o_acc[dc][j] * inv);
    }
  }
}

extern "C" void kernel_launch(void* const* d_in, const int* in_sizes, int n_in,
                              void* d_out, int out_size, void* d_ws, size_t ws_size,
                              hipStream_t stream)
{
  const float* x      = (const float*)d_in[0];
  const float* ln1_w  = (const float*)d_in[1];
  const float* ln1_b  = (const float*)d_in[2];
  const float* qkv_w  = (const float*)d_in[3];
  const float* qkv_b  = (const float*)d_in[4];
  const float* proj_w = (const float*)d_in[5];
  const float* proj_b = (const float*)d_in[6];
  const float* ln2_w  = (const float*)d_in[7];
  const float* ln2_b  = (const float*)d_in[8];
  const float* fc1_w  = (const float*)d_in[9];
  const float* fc1_b  = (const float*)d_in[10];
  const float* fc2_w  = (const float*)d_in[11];
  const float* fc2_b  = (const float*)d_in[12];

  char* base = (char*)d_ws;
  size_t off = 0;
  auto take = [&](size_t bytes) {
    void* r = base + off;
    off = (off + bytes + 255) & ~(size_t)255;
    return r;
  };
  unsigned short* wq = (unsigned short*)take(2304ull * 768 * 2);
  unsigned short* wp = (unsigned short*)take(768ull * 768 * 2);
  unsigned short* w1 = (unsigned short*)take(3072ull * 768 * 2);
  unsigned short* w2 = (unsigned short*)take(768ull * 3072 * 2);
  unsigned short* h  = (unsigned short*)take(4096ull * 768 * 2);   // LN out / attn O / LN2 out
  float* x2          = (float*)take(4096ull * 768 * 4);            // post-attn residual stream
  char* big          = (char*)take(4096ull * 3072 * 2);            // Q,K,V then FC1 act
  unsigned short* Qb = (unsigned short*)big;
  unsigned short* Kb = (unsigned short*)(big + 4096ull * 768 * 2);
  unsigned short* Vb = (unsigned short*)(big + 2ull * 4096 * 768 * 2);  // [b,h,d,2048]
  unsigned short* a2 = (unsigned short*)big;

  int n4;
  n4 = 2304 * 768 / 4; cvt_bf16<<<(n4 + 255) / 256, 256, 0, stream>>>(qkv_w, wq, n4);
  n4 = 768 * 768 / 4;  cvt_bf16<<<(n4 + 255) / 256, 256, 0, stream>>>(proj_w, wp, n4);
  n4 = 3072 * 768 / 4; cvt_bf16<<<(n4 + 255) / 256, 256, 0, stream>>>(fc1_w, w1, n4);
  n4 = 768 * 3072 / 4; cvt_bf16<<<(n4 + 255) / 256, 256, 0, stream>>>(fc2_w, w2, n4);

  ln_kernel<<<4096, 256, 0, stream>>>(x, ln1_w, ln1_b, h);
  gemm_nt<0><<<dim3(18, 32), 256, 0, stream>>>(h, wq, qkv_b, nullptr, Qb, Kb, Vb, 4096, 2304, 768);
  attn_fwd<<<dim3(32, 24), 256, 0, stream>>>(Qb, Kb, Vb, h);
  gemm_nt<1><<<dim3(6, 32), 256, 0, stream>>>(h, wp, proj_b, x, x2, nullptr, nullptr, 4096, 768, 768);
  ln_kernel<<<4096, 256, 0, stream>>>(x2, ln2_w, ln2_b, h);
  gemm_nt<2><<<dim3(24, 32), 256, 0, stream>>>(h, w1, fc1_b, nullptr, a2, nullptr, nullptr, 4096, 3072, 768);
  gemm_nt<3><<<dim3(6, 32), 256, 0, stream>>>(a2, w2, fc2_b, x2, d_out, nullptr, nullptr, 4096, 768, 3072);
}

// Round 8
// 212.983 us; speedup vs baseline: 1.1474x; 1.1045x over previous
//
#include <hip/hip_runtime.h>
#include <hip/hip_bf16.h>

typedef __attribute__((ext_vector_type(8))) short short8;
typedef __attribute__((ext_vector_type(4))) float f32x4;
typedef __attribute__((ext_vector_type(2))) int i32x2;
typedef __attribute__((ext_vector_type(4))) int i32x4;

// float -> bf16 bits, round-to-nearest-even
__device__ inline unsigned short f2bs(float f) {
  union { float f; unsigned u; } v; v.f = f;
  unsigned r = v.u + 0x7fff + ((v.u >> 16) & 1);
  return (unsigned short)(r >> 16);
}

__device__ inline unsigned pkbf(float a, float b) {
  __hip_bfloat162 h = __float22bfloat162_rn(float2{a, b});
  union { __hip_bfloat162 h; unsigned u; } c; c.h = h;
  return c.u;
}

__device__ inline void gload16(const void* g, void* l) {
  __builtin_amdgcn_global_load_lds((const __attribute__((address_space(1))) void*)g,
                                   (__attribute__((address_space(3))) void*)l,
                                   16, 0, 0);
}

// ---------------- weight fp32 -> bf16 ----------------
__global__ void cvt_bf16(const float* __restrict__ in, unsigned short* __restrict__ out, int n4) {
  int i = blockIdx.x * blockDim.x + threadIdx.x;
  if (i >= n4) return;
  float4 v = ((const float4*)in)[i];
  ushort4 o;
  o.x = f2bs(v.x); o.y = f2bs(v.y); o.z = f2bs(v.z); o.w = f2bs(v.w);
  ((ushort4*)out)[i] = o;
}

// ---------------- LayerNorm: fp32 in -> bf16 out ----------------
__global__ __launch_bounds__(256)
void ln_kernel(const float* __restrict__ x, const float* __restrict__ w,
               const float* __restrict__ bsh, unsigned short* __restrict__ out)
{
  const int row = blockIdx.x;
  const float* xr = x + (size_t)row * 768;
  float v[3];
  float s = 0.f, sq = 0.f;
#pragma unroll
  for (int i = 0; i < 3; ++i) {
    v[i] = xr[threadIdx.x + i * 256];
    s += v[i]; sq += v[i] * v[i];
  }
#pragma unroll
  for (int d = 1; d < 64; d <<= 1) {
    s  += __shfl_xor(s, d, 64);
    sq += __shfl_xor(sq, d, 64);
  }
  __shared__ float ss[4], ssq[4];
  const int wv = threadIdx.x >> 6;
  if ((threadIdx.x & 63) == 0) { ss[wv] = s; ssq[wv] = sq; }
  __syncthreads();
  s  = ss[0] + ss[1] + ss[2] + ss[3];
  sq = ssq[0] + ssq[1] + ssq[2] + ssq[3];
  const float mu = s * (1.0f / 768.0f);
  const float var = sq * (1.0f / 768.0f) - mu * mu;
  const float rstd = rsqrtf(var + 1e-5f);
#pragma unroll
  for (int i = 0; i < 3; ++i) {
    const int c = threadIdx.x + i * 256;
    out[(size_t)row * 768 + c] = f2bs((v[i] - mu) * rstd * w[c] + bsh[c]);
  }
}

// ---------------- split-K reduce: out = sum_s p[s] + bias + resid ----------------
template<int S>
__global__ __launch_bounds__(256)
void reduce_k(const float* __restrict__ p, const float* __restrict__ bias,
              const float* __restrict__ resid, float* __restrict__ out)
{
  const size_t MN = 4096ull * 768;
  const size_t i = ((size_t)blockIdx.x * 256 + threadIdx.x) * 4;
  float4 a = *(const float4*)(p + i);
#pragma unroll
  for (int s = 1; s < S; ++s) {
    float4 b = *(const float4*)(p + s * MN + i);
    a.x += b.x; a.y += b.y; a.z += b.z; a.w += b.w;
  }
  const int col = (int)(i % 768);
  float4 bb = *(const float4*)(bias + col);
  float4 rr = *(const float4*)(resid + i);
  a.x += bb.x + rr.x; a.y += bb.y + rr.y; a.z += bb.z + rr.z; a.w += bb.w + rr.w;
  *(float4*)(out + i) = a;
}

// ---------------- NT GEMM: C[m,n] = sum_k A[m,k]*Bw[n,k], bf16 in, f32 acc ----------------
// XCD-swizzled blockIdx, triple-buffered LDS, depth-2 counted-vmcnt prefetch.
// blockIdx.z = K-slice (Kslice elems starting at z*Kslice; row stride Kstride).
// EPI 0: qkv scatter -> Q,K bf16 [B,H,N,D] (Q pre-scaled by 8), V bf16 [B,H,D,N]
// EPI 1/3: + bias + resid -> f32 out
// EPI 2: + bias, GELU(exact) -> bf16 out
// EPI 4: raw f32 partial (no bias) -> out0 + z*M*N
template<int EPI>
__global__ __launch_bounds__(256, 3)
void gemm_nt(const unsigned short* __restrict__ A,
             const unsigned short* __restrict__ Bw,
             const float* __restrict__ bias,
             const float* __restrict__ resid,
             void* __restrict__ out0, void* __restrict__ out1, void* __restrict__ out2,
             int M, int N, int Kslice, int Kstride)
{
  __shared__ __align__(16) unsigned short As[3][128 * 32];
  __shared__ __align__(16) unsigned short Bs[3][128 * 32];
  const int tid = threadIdx.x;
  const int lane = tid & 63;
  const int w = tid >> 6;
  const int wr = w >> 1, wc = w & 1;
  const int l15 = lane & 15, g = lane >> 4;

  // bijective XCD swizzle within each z-slice (x*y grids divisible by 8)
  const int nwg = gridDim.x * gridDim.y;
  const int hw = blockIdx.y * gridDim.x + blockIdx.x;
  const int virt = (hw & 7) * (nwg >> 3) + (hw >> 3);
  const int m0 = (virt / gridDim.x) * 128;
  const int n0 = (virt % gridDim.x) * 128;
  const int kbase = blockIdx.z * Kslice;

  f32x4 acc[4][4];
#pragma unroll
  for (int m = 0; m < 4; ++m)
#pragma unroll
    for (int n = 0; n < 4; ++n)
      acc[m][n] = (f32x4){0.f, 0.f, 0.f, 0.f};

  auto stage = [&](int buf, int k0) {
#pragma unroll
    for (int i = 0; i < 2; ++i) {
      const int f = tid + i * 256;
      const int row = f >> 2, c8 = f & 3;
      const int sc = c8 ^ (row & 3);
      gload16(A  + (size_t)(m0 + row) * Kstride + kbase + k0 + sc * 8, (char*)&As[buf][0] + f * 16);
      gload16(Bw + (size_t)(n0 + row) * Kstride + kbase + k0 + sc * 8, (char*)&Bs[buf][0] + f * 16);
    }
  };

  const int NT = Kslice >> 5;
  stage(0, 0);
  stage(1, 32);

  for (int t = 0; t < NT; ++t) {
    const int buf = t % 3;
    if (t + 2 < NT) {
      stage((t + 2) % 3, (t + 2) * 32);
      asm volatile("s_waitcnt vmcnt(8)" ::: "memory");
    } else if (t + 1 < NT) {
      asm volatile("s_waitcnt vmcnt(4)" ::: "memory");
    } else {
      asm volatile("s_waitcnt vmcnt(0)" ::: "memory");
    }
    __builtin_amdgcn_s_barrier();
    asm volatile("" ::: "memory");

    short8 af[4], bfr[4];
#pragma unroll
    for (int m = 0; m < 4; ++m) {
      const int r = wr * 64 + m * 16 + l15;
      af[m] = *(const short8*)((const char*)&As[buf][0] + ((size_t)r * 32 + (g ^ (r & 3)) * 8) * 2);
    }
#pragma unroll
    for (int n = 0; n < 4; ++n) {
      const int r = wc * 64 + n * 16 + l15;
      bfr[n] = *(const short8*)((const char*)&Bs[buf][0] + ((size_t)r * 32 + (g ^ (r & 3)) * 8) * 2);
    }
#pragma unroll
    for (int m = 0; m < 4; ++m)
#pragma unroll
      for (int n = 0; n < 4; ++n)
        acc[m][n] = __builtin_amdgcn_mfma_f32_16x16x32_bf16(af[m], bfr[n], acc[m][n], 0, 0, 0);

    asm volatile("" ::: "memory");
    __builtin_amdgcn_s_barrier();
  }

  // epilogue: C/D layout col = lane&15, row = (lane>>4)*4 + j
#pragma unroll
  for (int m = 0; m < 4; ++m) {
    const int gmBase = m0 + wr * 64 + m * 16 + g * 4;
#pragma unroll
    for (int n = 0; n < 4; ++n) {
      const int gn = n0 + wc * 64 + n * 16 + l15;
      const float bval = (EPI == 4) ? 0.0f : bias[gn];
      float vj[4];
#pragma unroll
      for (int j = 0; j < 4; ++j) vj[j] = acc[m][n][j] + bval;
      if (EPI == 0) {
        const int three = gn / 768;
        const int hh = (gn % 768) >> 6;
        const int d = gn & 63;
        const int bb = gmBase >> 11, t = gmBase & 2047;
        if (three == 2) {
          // V transposed: [b,h,d,2048], 4 consecutive tokens -> one 8B store
          ushort4 pk;
          pk.x = f2bs(vj[0]); pk.y = f2bs(vj[1]); pk.z = f2bs(vj[2]); pk.w = f2bs(vj[3]);
          *(ushort4*)((unsigned short*)out2 + (((size_t)bb * 12 + hh) * 64 + d) * 2048 + t) = pk;
        } else {
          unsigned short* dst = (three == 0) ? (unsigned short*)out0 : (unsigned short*)out1;
#pragma unroll
          for (int j = 0; j < 4; ++j) {
            float v = vj[j];
            if (three == 0) v *= 8.0f;   // fold attention scale into Q
            dst[(((size_t)bb * 12 + hh) * 2048 + (t + j)) * 64 + d] = f2bs(v);
          }
        }
      } else if (EPI == 1 || EPI == 3) {
#pragma unroll
        for (int j = 0; j < 4; ++j) {
          const int gm = gmBase + j;
          ((float*)out0)[(size_t)gm * N + gn] = vj[j] + resid[(size_t)gm * N + gn];
        }
      } else if (EPI == 2) {
#pragma unroll
        for (int j = 0; j < 4; ++j) {
          const int gm = gmBase + j;
          const float ge = 0.5f * vj[j] * (1.0f + erff(vj[j] * 0.70710678f));
          ((unsigned short*)out0)[(size_t)gm * N + gn] = f2bs(ge);
        }
      } else {  // EPI == 4: raw partial
        float* po = (float*)out0 + (size_t)blockIdx.z * M * N;
#pragma unroll
        for (int j = 0; j < 4; ++j) {
          const int gm = gmBase + j;
          po[(size_t)gm * N + gn] = vj[j];
        }
      }
    }
  }
}

// ---------------- Flash attention fwd v6 ----------------
// v5 + launch_bounds(256,4) for 4 blocks/CU occupancy.
// Swapped QK^T (lane-local P rows), frag-ordered K staging, V^T global layout
// staged into XOR-swizzled [64d][64k] LDS, PV B-frags via two 8B LDS loads.
// grid 768 linear (XCD-swizzled), 256 threads (4 waves), wave owns 16 q-rows.
__global__ __launch_bounds__(256, 4)
void attn_fwd(const unsigned short* __restrict__ Q,
              const unsigned short* __restrict__ K,
              const unsigned short* __restrict__ Vt,
              unsigned short* __restrict__ O)
{
  __shared__ __align__(1024) unsigned short Ks[2][8 * 512];  // frag f=n*2+kc, lane*16B
  __shared__ __align__(1024) unsigned short Vs[2][4096];     // [64d][64k], 16B-block swizzle t^=(d&7)
  const int tid = threadIdx.x, lane = tid & 63, w = tid >> 6;
  const int l15 = lane & 15, g = lane >> 4;

  // bijective XCD swizzle: nwg=768; each XCD gets 3 bh-groups x 32 q-blocks
  const int hw = blockIdx.y * gridDim.x + blockIdx.x;
  const int virt = (hw & 7) * 96 + (hw >> 3);
  const int qblk = virt & 31;
  const int bh = virt >> 5;
  const int b = bh / 12, h = bh % 12;
  const int q0 = qblk * 64;
  const unsigned short* Qb = Q  + (size_t)bh * 2048 * 64;
  const unsigned short* Kb = K  + (size_t)bh * 2048 * 64;
  const unsigned short* Vb = Vt + (size_t)bh * 64 * 2048;

  const int qr = q0 + w * 16 + l15;
  short8 qf[2];
  qf[0] = *(const short8*)(Qb + (size_t)qr * 64 + g * 8);
  qf[1] = *(const short8*)(Qb + (size_t)qr * 64 + 32 + g * 8);

  float m_run = -1e30f, l_run = 0.f;
  f32x4 o_acc[4];
#pragma unroll
  for (int dc = 0; dc < 4; ++dc) o_acc[dc] = (f32x4){0.f, 0.f, 0.f, 0.f};

  const int vtok = ((lane & 7) ^ (lane >> 3)) * 8;  // pre-swizzled source token offset

  auto stage = [&](int buf, int kb) {
#pragma unroll
    for (int i = 0; i < 2; ++i) {
      const int f = w * 2 + i;
      const int n = f >> 1, kc = f & 1;
      gload16(Kb + (size_t)(kb + n * 16 + l15) * 64 + kc * 32 + g * 8,
              (char*)&Ks[buf][0] + f * 1024);
    }
#pragma unroll
    for (int i = 0; i < 2; ++i) {
      const int c = w * 2 + i;
      const int d = c * 8 + (lane >> 3);
      gload16(Vb + (size_t)d * 2048 + kb + vtok,
              (char*)&Vs[buf][0] + c * 1024);
    }
  };

  stage(0, 0);
  __syncthreads();   // drain prologue (qf + tile0) once
  int cur = 0;

  for (int t = 0; t < 32; ++t) {
    if (t < 31) {
      stage(cur ^ 1, (t + 1) * 64);
      asm volatile("s_waitcnt vmcnt(4)" ::: "memory");
    } else {
      asm volatile("s_waitcnt vmcnt(0)" ::: "memory");
    }
    __builtin_amdgcn_s_barrier();
    asm volatile("" ::: "memory");

    // --- S^T = K · Q^T : lane holds S[q=l15][key = n*16 + 4g + j] ---
    f32x4 s2[4];
#pragma unroll
    for (int n = 0; n < 4; ++n) s2[n] = (f32x4){0.f, 0.f, 0.f, 0.f};
    __builtin_amdgcn_s_setprio(1);
#pragma unroll
    for (int n = 0; n < 4; ++n) {
      short8 kf0 = *(const short8*)(&Ks[cur][(n * 2 + 0) * 512 + lane * 8]);
      short8 kf1 = *(const short8*)(&Ks[cur][(n * 2 + 1) * 512 + lane * 8]);
      s2[n] = __builtin_amdgcn_mfma_f32_16x16x32_bf16(kf0, qf[0], s2[n], 0, 0, 0);
      s2[n] = __builtin_amdgcn_mfma_f32_16x16x32_bf16(kf1, qf[1], s2[n], 0, 0, 0);
    }
    __builtin_amdgcn_s_setprio(0);

    // --- online softmax, fully in-register (q = l15 per lane) ---
    float mx = s2[0][0];
#pragma unroll
    for (int n = 0; n < 4; ++n)
#pragma unroll
      for (int j = 0; j < 4; ++j) mx = fmaxf(mx, s2[n][j]);
    mx = fmaxf(mx, __shfl_xor(mx, 16, 64));
    mx = fmaxf(mx, __shfl_xor(mx, 32, 64));
    if (__any(mx > m_run)) {
      const float mn = fmaxf(m_run, mx);
      const float alpha = __expf(m_run - mn);
      m_run = mn;
      l_run *= alpha;
#pragma unroll
      for (int j = 0; j < 4; ++j) {
        const float aB = __shfl(alpha, (lane & 48) | (g * 4 + j), 64);
#pragma unroll
        for (int dc = 0; dc < 4; ++dc) o_acc[dc][j] *= aB;
      }
    }
    float e[4][4];
    float rs = 0.f;
#pragma unroll
    for (int n = 0; n < 4; ++n)
#pragma unroll
      for (int j = 0; j < 4; ++j) {
        e[n][j] = __expf(s2[n][j] - m_run);
        rs += e[n][j];
      }
    rs += __shfl_xor(rs, 16, 64);
    rs += __shfl_xor(rs, 32, 64);
    l_run += rs;

    // --- pack P fragments: slot s=g*8+i -> key (2kc + (i>=4))*16 + 4g + (i&3) ---
    unsigned pw[2][4];
#pragma unroll
    for (int kc = 0; kc < 2; ++kc) {
      pw[kc][0] = pkbf(e[2 * kc][0],     e[2 * kc][1]);
      pw[kc][1] = pkbf(e[2 * kc][2],     e[2 * kc][3]);
      pw[kc][2] = pkbf(e[2 * kc + 1][0], e[2 * kc + 1][1]);
      pw[kc][3] = pkbf(e[2 * kc + 1][2], e[2 * kc + 1][3]);
    }

    // --- O += P · V : V-frags from swizzled [d][k] LDS, two 8B loads each ---
    const char* vsb = (const char*)&Vs[cur][0];
    const unsigned sw = (unsigned)(l15 & 7) << 4;
#pragma unroll
    for (int kc = 0; kc < 2; ++kc) {
      i32x4 pt; pt.x = (int)pw[kc][0]; pt.y = (int)pw[kc][1]; pt.z = (int)pw[kc][2]; pt.w = (int)pw[kc][3];
      short8 pf = *(short8*)&pt;
      __builtin_amdgcn_s_setprio(1);
#pragma unroll
      for (int dc = 0; dc < 4; ++dc) {
        const unsigned row = (unsigned)(dc * 16 + l15) * 128;
        i32x2 ra  = *(const i32x2*)(vsb + row + (((unsigned)(kc * 64 + g * 8)) ^ sw));
        i32x2 rb2 = *(const i32x2*)(vsb + row + (((unsigned)(kc * 64 + 32 + g * 8)) ^ sw));
        i32x4 vt4; vt4.x = ra.x; vt4.y = ra.y; vt4.z = rb2.x; vt4.w = rb2.y;
        short8 vf = *(short8*)&vt4;
        o_acc[dc] = __builtin_amdgcn_mfma_f32_16x16x32_bf16(pf, vf, o_acc[dc], 0, 0, 0);
      }
      __builtin_amdgcn_s_setprio(0);
    }

    asm volatile("" ::: "memory");
    __builtin_amdgcn_s_barrier();   // release buffers; prefetch stays in flight
    cur ^= 1;
  }

  // --- epilogue: o_acc[dc][j] = O[q = q0+w*16+g*4+j][d = dc*16+l15] ---
#pragma unroll
  for (int j = 0; j < 4; ++j) {
    const float lB = __shfl(l_run, (lane & 48) | (g * 4 + j), 64);
    const float inv = 1.0f / lB;
    const int qrow = q0 + w * 16 + g * 4 + j;
#pragma unroll
    for (int dc = 0; dc < 4; ++dc) {
      O[((size_t)b * 2048 + qrow) * 768 + h * 64 + dc * 16 + l15] = f2bs(o_acc[dc][j] * inv);
    }
  }
}

extern "C" void kernel_launch(void* const* d_in, const int* in_sizes, int n_in,
                              void* d_out, int out_size, void* d_ws, size_t ws_size,
                              hipStream_t stream)
{
  const float* x      = (const float*)d_in[0];
  const float* ln1_w  = (const float*)d_in[1];
  const float* ln1_b  = (const float*)d_in[2];
  const float* qkv_w  = (const float*)d_in[3];
  const float* qkv_b  = (const float*)d_in[4];
  const float* proj_w = (const float*)d_in[5];
  const float* proj_b = (const float*)d_in[6];
  const float* ln2_w  = (const float*)d_in[7];
  const float* ln2_b  = (const float*)d_in[8];
  const float* fc1_w  = (const float*)d_in[9];
  const float* fc1_b  = (const float*)d_in[10];
  const float* fc2_w  = (const float*)d_in[11];
  const float* fc2_b  = (const float*)d_in[12];

  char* base = (char*)d_ws;
  size_t off = 0;
  auto take = [&](size_t bytes) {
    void* r = base + off;
    off = (off + bytes + 255) & ~(size_t)255;
    return r;
  };
  unsigned short* wq = (unsigned short*)take(2304ull * 768 * 2);
  unsigned short* wp = (unsigned short*)take(768ull * 768 * 2);
  unsigned short* w1 = (unsigned short*)take(3072ull * 768 * 2);
  unsigned short* w2 = (unsigned short*)take(768ull * 3072 * 2);
  unsigned short* h  = (unsigned short*)take(4096ull * 768 * 2);   // LN out / attn O / LN2 out
  float* x2          = (float*)take(4096ull * 768 * 4);            // post-attn residual stream
  char* big          = (char*)take(4096ull * 3072 * 2);            // Q,K,V then FC1 act
  unsigned short* Qb = (unsigned short*)big;
  unsigned short* Kb = (unsigned short*)(big + 4096ull * 768 * 2);
  unsigned short* Vb = (unsigned short*)(big + 2ull * 4096 * 768 * 2);  // [b,h,d,2048]
  unsigned short* a2 = (unsigned short*)big;
  float* part        = (float*)take(4ull * 4096 * 768 * 4);        // split-K partials (50.3 MB)
  const bool can_split = off <= ws_size;

  int n4;
  n4 = 2304 * 768 / 4; cvt_bf16<<<(n4 + 255) / 256, 256, 0, stream>>>(qkv_w, wq, n4);
  n4 = 768 * 768 / 4;  cvt_bf16<<<(n4 + 255) / 256, 256, 0, stream>>>(proj_w, wp, n4);
  n4 = 3072 * 768 / 4; cvt_bf16<<<(n4 + 255) / 256, 256, 0, stream>>>(fc1_w, w1, n4);
  n4 = 768 * 3072 / 4; cvt_bf16<<<(n4 + 255) / 256, 256, 0, stream>>>(fc2_w, w2, n4);

  ln_kernel<<<4096, 256, 0, stream>>>(x, ln1_w, ln1_b, h);
  gemm_nt<0><<<dim3(18, 32), 256, 0, stream>>>(h, wq, qkv_b, nullptr, Qb, Kb, Vb, 4096, 2304, 768, 768);
  attn_fwd<<<dim3(32, 24), 256, 0, stream>>>(Qb, Kb, Vb, h);

  if (can_split) {
    gemm_nt<4><<<dim3(6, 32, 2), 256, 0, stream>>>(h, wp, nullptr, nullptr, part, nullptr, nullptr, 4096, 768, 384, 768);
    reduce_k<2><<<3072, 256, 0, stream>>>(part, proj_b, x, x2);
  } else {
    gemm_nt<1><<<dim3(6, 32), 256, 0, stream>>>(h, wp, proj_b, x, x2, nullptr, nullptr, 4096, 768, 768, 768);
  }

  ln_kernel<<<4096, 256, 0, stream>>>(x2, ln2_w, ln2_b, h);
  gemm_nt<2><<<dim3(24, 32), 256, 0, stream>>>(h, w1, fc1_b, nullptr, a2, nullptr, nullptr, 4096, 3072, 768, 768);

  if (can_split) {
    gemm_nt<4><<<dim3(6, 32, 4), 256, 0, stream>>>(a2, w2, nullptr, nullptr, part, nullptr, nullptr, 4096, 768, 768, 3072);
    reduce_k<4><<<3072, 256, 0, stream>>>(part, fc2_b, x2, (float*)d_out);
  } else {
    gemm_nt<3><<<dim3(6, 32), 256, 0, stream>>>(a2, w2, fc2_b, x2, d_out, nullptr, nullptr, 4096, 768, 3072, 3072);
  }
}

// Round 9
// 206.980 us; speedup vs baseline: 1.1807x; 1.0290x over previous
//
#include <hip/hip_runtime.h>
#include <hip/hip_bf16.h>

typedef __attribute__((ext_vector_type(8))) short short8;
typedef __attribute__((ext_vector_type(4))) float f32x4;
typedef __attribute__((ext_vector_type(4))) int i32x4;

// float -> bf16 bits, round-to-nearest-even
__device__ inline unsigned short f2bs(float f) {
  union { float f; unsigned u; } v; v.f = f;
  unsigned r = v.u + 0x7fff + ((v.u >> 16) & 1);
  return (unsigned short)(r >> 16);
}

__device__ inline unsigned pkbf(float a, float b) {
  __hip_bfloat162 h = __float22bfloat162_rn(float2{a, b});
  union { __hip_bfloat162 h; unsigned u; } c; c.h = h;
  return c.u;
}

__device__ inline float exp2v(float x) {  // 2^x via v_exp_f32 (1 VALU op)
  float r; asm("v_exp_f32 %0, %1" : "=v"(r) : "v"(x)); return r;
}

__device__ inline void gload16(const void* g, void* l) {
  __builtin_amdgcn_global_load_lds((const __attribute__((address_space(1))) void*)g,
                                   (__attribute__((address_space(3))) void*)l,
                                   16, 0, 0);
}

// ---------------- weight fp32 -> bf16 ----------------
__global__ void cvt_bf16(const float* __restrict__ in, unsigned short* __restrict__ out, int n4) {
  int i = blockIdx.x * blockDim.x + threadIdx.x;
  if (i >= n4) return;
  float4 v = ((const float4*)in)[i];
  ushort4 o;
  o.x = f2bs(v.x); o.y = f2bs(v.y); o.z = f2bs(v.z); o.w = f2bs(v.w);
  ((ushort4*)out)[i] = o;
}

// ---------------- LayerNorm: fp32 in -> bf16 out ----------------
__global__ __launch_bounds__(256)
void ln_kernel(const float* __restrict__ x, const float* __restrict__ w,
               const float* __restrict__ bsh, unsigned short* __restrict__ out)
{
  const int row = blockIdx.x;
  const float* xr = x + (size_t)row * 768;
  float v[3];
  float s = 0.f, sq = 0.f;
#pragma unroll
  for (int i = 0; i < 3; ++i) {
    v[i] = xr[threadIdx.x + i * 256];
    s += v[i]; sq += v[i] * v[i];
  }
#pragma unroll
  for (int d = 1; d < 64; d <<= 1) {
    s  += __shfl_xor(s, d, 64);
    sq += __shfl_xor(sq, d, 64);
  }
  __shared__ float ss[4], ssq[4];
  const int wv = threadIdx.x >> 6;
  if ((threadIdx.x & 63) == 0) { ss[wv] = s; ssq[wv] = sq; }
  __syncthreads();
  s  = ss[0] + ss[1] + ss[2] + ss[3];
  sq = ssq[0] + ssq[1] + ssq[2] + ssq[3];
  const float mu = s * (1.0f / 768.0f);
  const float var = sq * (1.0f / 768.0f) - mu * mu;
  const float rstd = rsqrtf(var + 1e-5f);
#pragma unroll
  for (int i = 0; i < 3; ++i) {
    const int c = threadIdx.x + i * 256;
    out[(size_t)row * 768 + c] = f2bs((v[i] - mu) * rstd * w[c] + bsh[c]);
  }
}

// ---------------- split-K reduce: out = sum_s p[s] + bias + resid ----------------
template<int S>
__global__ __launch_bounds__(256)
void reduce_k(const float* __restrict__ p, const float* __restrict__ bias,
              const float* __restrict__ resid, float* __restrict__ out)
{
  const size_t MN = 4096ull * 768;
  const size_t i = ((size_t)blockIdx.x * 256 + threadIdx.x) * 4;
  float4 a = *(const float4*)(p + i);
#pragma unroll
  for (int s = 1; s < S; ++s) {
    float4 b = *(const float4*)(p + s * MN + i);
    a.x += b.x; a.y += b.y; a.z += b.z; a.w += b.w;
  }
  const int col = (int)(i % 768);
  float4 bb = *(const float4*)(bias + col);
  float4 rr = *(const float4*)(resid + i);
  a.x += bb.x + rr.x; a.y += bb.y + rr.y; a.z += bb.z + rr.z; a.w += bb.w + rr.w;
  *(float4*)(out + i) = a;
}

// ---------------- NT GEMM: C[m,n] = sum_k A[m,k]*Bw[n,k], bf16 in, f32 acc ----------------
// XCD-swizzled blockIdx, 3-buffer LDS, single barrier/K-step, counted vmcnt.
// EPI 0: qkv scatter -> Q (pre-scaled by 8*log2e), K bf16 [B,H,N,D]; V frag-major
// EPI 1/3: + bias + resid -> f32 out;  EPI 2: + bias, GELU -> bf16;  EPI 4: raw partial
template<int EPI>
__global__ __launch_bounds__(256, 3)
void gemm_nt(const unsigned short* __restrict__ A,
             const unsigned short* __restrict__ Bw,
             const float* __restrict__ bias,
             const float* __restrict__ resid,
             void* __restrict__ out0, void* __restrict__ out1, void* __restrict__ out2,
             int M, int N, int Kslice, int Kstride)
{
  __shared__ __align__(16) unsigned short As[3][128 * 32];
  __shared__ __align__(16) unsigned short Bs[3][128 * 32];
  const int tid = threadIdx.x;
  const int lane = tid & 63;
  const int w = tid >> 6;
  const int wr = w >> 1, wc = w & 1;
  const int l15 = lane & 15, g = lane >> 4;

  const int nwg = gridDim.x * gridDim.y;
  const int hw = blockIdx.y * gridDim.x + blockIdx.x;
  const int virt = (hw & 7) * (nwg >> 3) + (hw >> 3);
  const int m0 = (virt / gridDim.x) * 128;
  const int n0 = (virt % gridDim.x) * 128;
  const int kbase = blockIdx.z * Kslice;

  f32x4 acc[4][4];
#pragma unroll
  for (int m = 0; m < 4; ++m)
#pragma unroll
    for (int n = 0; n < 4; ++n)
      acc[m][n] = (f32x4){0.f, 0.f, 0.f, 0.f};

  auto stage = [&](int buf, int k0) {
#pragma unroll
    for (int i = 0; i < 2; ++i) {
      const int f = tid + i * 256;
      const int row = f >> 2, c8 = f & 3;
      const int sc = c8 ^ (row & 3);
      gload16(A  + (size_t)(m0 + row) * Kstride + kbase + k0 + sc * 8, (char*)&As[buf][0] + f * 16);
      gload16(Bw + (size_t)(n0 + row) * Kstride + kbase + k0 + sc * 8, (char*)&Bs[buf][0] + f * 16);
    }
  };

  const int NT = Kslice >> 5;
  stage(0, 0);
  stage(1, 32);

  for (int t = 0; t < NT; ++t) {
    const int buf = t % 3;
    if (t + 1 < NT) {
      asm volatile("s_waitcnt vmcnt(4)" ::: "memory");
    } else {
      asm volatile("s_waitcnt vmcnt(0)" ::: "memory");
    }
    __builtin_amdgcn_s_barrier();
    asm volatile("" ::: "memory");
    if (t + 2 < NT) stage((t + 2) % 3, (t + 2) * 32);

    short8 af[4], bfr[4];
#pragma unroll
    for (int m = 0; m < 4; ++m) {
      const int r = wr * 64 + m * 16 + l15;
      af[m] = *(const short8*)((const char*)&As[buf][0] + ((size_t)r * 32 + (g ^ (r & 3)) * 8) * 2);
    }
#pragma unroll
    for (int n = 0; n < 4; ++n) {
      const int r = wc * 64 + n * 16 + l15;
      bfr[n] = *(const short8*)((const char*)&Bs[buf][0] + ((size_t)r * 32 + (g ^ (r & 3)) * 8) * 2);
    }
#pragma unroll
    for (int m = 0; m < 4; ++m)
#pragma unroll
      for (int n = 0; n < 4; ++n)
        acc[m][n] = __builtin_amdgcn_mfma_f32_16x16x32_bf16(af[m], bfr[n], acc[m][n], 0, 0, 0);
    asm volatile("" ::: "memory");
  }

  // epilogue: C/D layout col = lane&15, row = (lane>>4)*4 + j
#pragma unroll
  for (int m = 0; m < 4; ++m) {
    const int gmBase = m0 + wr * 64 + m * 16 + g * 4;
#pragma unroll
    for (int n = 0; n < 4; ++n) {
      const int gn = n0 + wc * 64 + n * 16 + l15;
      const float bval = (EPI == 4) ? 0.0f : bias[gn];
      float vj[4];
#pragma unroll
      for (int j = 0; j < 4; ++j) vj[j] = acc[m][n][j] + bval;
      if (EPI == 0) {
        const int three = gn / 768;
        const int hh = (gn % 768) >> 6;
        const int d = gn & 63;
        const int bb = gmBase >> 11, t = gmBase & 2047;
        if (three == 2) {
          // V frag-major: pos = (((bh*32+ktile)*8 + (d>>4)*2 + (kt>>5))*64
          //                      + ((kt>>2)&3)*16 + (d&15))*8 + ((kt>>4)&1)*4 + j
          ushort4 pk;
          pk.x = f2bs(vj[0]); pk.y = f2bs(vj[1]); pk.z = f2bs(vj[2]); pk.w = f2bs(vj[3]);
          const int kt = t & 63;
          const size_t pos = ((((size_t)(bb * 12 + hh) * 32 + (t >> 6)) * 8 + (d >> 4) * 2 + (kt >> 5)) * 64
                              + ((kt >> 2) & 3) * 16 + (d & 15)) * 8 + ((kt >> 4) & 1) * 4;
          *(ushort4*)((unsigned short*)out2 + pos) = pk;
        } else {
          unsigned short* dst = (three == 0) ? (unsigned short*)out0 : (unsigned short*)out1;
#pragma unroll
          for (int j = 0; j < 4; ++j) {
            float v = vj[j];
            if (three == 0) v *= 11.5415603f;   // 8 * log2(e): attention in exp2 domain
            dst[(((size_t)bb * 12 + hh) * 2048 + (t + j)) * 64 + d] = f2bs(v);
          }
        }
      } else if (EPI == 1 || EPI == 3) {
#pragma unroll
        for (int j = 0; j < 4; ++j) {
          const int gm = gmBase + j;
          ((float*)out0)[(size_t)gm * N + gn] = vj[j] + resid[(size_t)gm * N + gn];
        }
      } else if (EPI == 2) {
#pragma unroll
        for (int j = 0; j < 4; ++j) {
          const int gm = gmBase + j;
          const float ge = 0.5f * vj[j] * (1.0f + erff(vj[j] * 0.70710678f));
          ((unsigned short*)out0)[(size_t)gm * N + gn] = f2bs(ge);
        }
      } else {  // EPI == 4: raw partial
        float* po = (float*)out0 + (size_t)blockIdx.z * M * N;
#pragma unroll
        for (int j = 0; j < 4; ++j) {
          const int gm = gmBase + j;
          po[(size_t)gm * N + gn] = vj[j];
        }
      }
    }
  }
}

// ---------------- Flash attention fwd v7 ----------------
// Swapped QK^T (lane-local P rows); K frag-ordered LDS; V frag-major global ->
// linear staging -> single conflict-free ds_read_b128 per PV fragment.
// 3-buffer, single barrier per tile, counted vmcnt. exp2-domain softmax
// (scale folded into Q), deferred l-sum reduce.
// grid 768 linear (XCD-swizzled), 256 threads (4 waves), wave owns 16 q-rows.
__global__ __launch_bounds__(256, 3)
void attn_fwd(const unsigned short* __restrict__ Q,
              const unsigned short* __restrict__ K,
              const unsigned short* __restrict__ Vf,
              unsigned short* __restrict__ O)
{
  __shared__ __align__(1024) unsigned short Ks[3][4096];  // frag f=n*2+kc at f*512+lane*8
  __shared__ __align__(1024) unsigned short Vs[3][4096];  // frag-major linear copy of Vf tile
  const int tid = threadIdx.x, lane = tid & 63, w = tid >> 6;
  const int l15 = lane & 15, g = lane >> 4;

  // bijective XCD swizzle: nwg=768; each XCD gets 3 bh-groups x 32 q-blocks
  const int hw = blockIdx.y * gridDim.x + blockIdx.x;
  const int virt = (hw & 7) * 96 + (hw >> 3);
  const int qblk = virt & 31;
  const int bh = virt >> 5;
  const int b = bh / 12, h = bh % 12;
  const int q0 = qblk * 64;
  const unsigned short* Qb = Q  + (size_t)bh * 2048 * 64;
  const unsigned short* Kb = K  + (size_t)bh * 2048 * 64;
  const unsigned short* Vb = Vf + (size_t)bh * 2048 * 64;  // frag-major per bh

  const int qr = q0 + w * 16 + l15;
  short8 qf[2];
  qf[0] = *(const short8*)(Qb + (size_t)qr * 64 + g * 8);
  qf[1] = *(const short8*)(Qb + (size_t)qr * 64 + 32 + g * 8);

  float m_run = -1e30f, l_part = 0.f;
  f32x4 o_acc[4];
#pragma unroll
  for (int dc = 0; dc < 4; ++dc) o_acc[dc] = (f32x4){0.f, 0.f, 0.f, 0.f};

  auto stage = [&](int buf, int tIdx) {
    const int kb = tIdx * 64;
#pragma unroll
    for (int i = 0; i < 2; ++i) {
      const int f = w * 2 + i;
      const int n = f >> 1, kc = f & 1;
      gload16(Kb + (size_t)(kb + n * 16 + l15) * 64 + kc * 32 + g * 8,
              (char*)&Ks[buf][0] + f * 1024);
    }
#pragma unroll
    for (int i = 0; i < 2; ++i) {
      const int chunk = tid + i * 256;
      gload16(Vb + (size_t)tIdx * 4096 + chunk * 8,
              (char*)&Vs[buf][0] + chunk * 16);
    }
  };

  stage(0, 0);
  stage(1, 1);

  for (int t = 0; t < 32; ++t) {
    const int buf = t % 3;
    if (t < 31) {
      asm volatile("s_waitcnt vmcnt(4)" ::: "memory");
    } else {
      asm volatile("s_waitcnt vmcnt(0)" ::: "memory");
    }
    __builtin_amdgcn_s_barrier();
    asm volatile("" ::: "memory");
    if (t < 30) stage((t + 2) % 3, t + 2);

    // --- S^T = K · Q^T : lane holds S[q=l15][key = n*16 + 4g + j] (log2 domain) ---
    f32x4 s2[4];
#pragma unroll
    for (int n = 0; n < 4; ++n) s2[n] = (f32x4){0.f, 0.f, 0.f, 0.f};
    __builtin_amdgcn_s_setprio(1);
#pragma unroll
    for (int n = 0; n < 4; ++n) {
      short8 kf0 = *(const short8*)(&Ks[buf][(n * 2 + 0) * 512 + lane * 8]);
      short8 kf1 = *(const short8*)(&Ks[buf][(n * 2 + 1) * 512 + lane * 8]);
      s2[n] = __builtin_amdgcn_mfma_f32_16x16x32_bf16(kf0, qf[0], s2[n], 0, 0, 0);
      s2[n] = __builtin_amdgcn_mfma_f32_16x16x32_bf16(kf1, qf[1], s2[n], 0, 0, 0);
    }
    __builtin_amdgcn_s_setprio(0);

    // --- online softmax (exp2 domain), q = l15 per lane ---
    float mx = s2[0][0];
#pragma unroll
    for (int n = 0; n < 4; ++n)
#pragma unroll
      for (int j = 0; j < 4; ++j) mx = fmaxf(mx, s2[n][j]);
    mx = fmaxf(mx, __shfl_xor(mx, 16, 64));
    mx = fmaxf(mx, __shfl_xor(mx, 32, 64));
    if (__any(mx > m_run)) {
      const float mn = fmaxf(m_run, mx);
      const float alpha = exp2v(m_run - mn);
      m_run = mn;
      l_part *= alpha;
#pragma unroll
      for (int j = 0; j < 4; ++j) {
        const float aB = __shfl(alpha, (lane & 48) | (g * 4 + j), 64);
#pragma unroll
        for (int dc = 0; dc < 4; ++dc) o_acc[dc][j] *= aB;
      }
    }
    float e[4][4];
    float rs = 0.f;
#pragma unroll
    for (int n = 0; n < 4; ++n)
#pragma unroll
      for (int j = 0; j < 4; ++j) {
        e[n][j] = exp2v(s2[n][j] - m_run);
        rs += e[n][j];
      }
    l_part += rs;   // per-lane partial; cross-lane reduce deferred to epilogue

    // --- pack P fragments: slot i -> key (2kc + (i>=4))*16 + 4g + (i&3) ---
    unsigned pw[2][4];
#pragma unroll
    for (int kc = 0; kc < 2; ++kc) {
      pw[kc][0] = pkbf(e[2 * kc][0],     e[2 * kc][1]);
      pw[kc][1] = pkbf(e[2 * kc][2],     e[2 * kc][3]);
      pw[kc][2] = pkbf(e[2 * kc + 1][0], e[2 * kc + 1][1]);
      pw[kc][3] = pkbf(e[2 * kc + 1][2], e[2 * kc + 1][3]);
    }

    // --- O += P · V : frag-major Vs, one b128 per fragment, conflict-free ---
    const char* vsb = (const char*)&Vs[buf][0];
    __builtin_amdgcn_s_setprio(1);
#pragma unroll
    for (int kc = 0; kc < 2; ++kc) {
      i32x4 pt; pt.x = (int)pw[kc][0]; pt.y = (int)pw[kc][1]; pt.z = (int)pw[kc][2]; pt.w = (int)pw[kc][3];
      short8 pf = *(short8*)&pt;
#pragma unroll
      for (int dc = 0; dc < 4; ++dc) {
        short8 vfr = *(const short8*)(vsb + (((dc * 2 + kc) * 64 + lane) * 16));
        o_acc[dc] = __builtin_amdgcn_mfma_f32_16x16x32_bf16(pf, vfr, o_acc[dc], 0, 0, 0);
      }
    }
    __builtin_amdgcn_s_setprio(0);
    asm volatile("" ::: "memory");
  }

  // --- epilogue: reduce l across lane groups, then write O ---
  l_part += __shfl_xor(l_part, 16, 64);
  l_part += __shfl_xor(l_part, 32, 64);
#pragma unroll
  for (int j = 0; j < 4; ++j) {
    const float lB = __shfl(l_part, (lane & 48) | (g * 4 + j), 64);
    const float inv = 1.0f / lB;
    const int qrow = q0 + w * 16 + g * 4 + j;
#pragma unroll
    for (int dc = 0; dc < 4; ++dc) {
      O[((size_t)b * 2048 + qrow) * 768 + h * 64 + dc * 16 + l15] = f2bs(o_acc[dc][j] * inv);
    }
  }
}

extern "C" void kernel_launch(void* const* d_in, const int* in_sizes, int n_in,
                              void* d_out, int out_size, void* d_ws, size_t ws_size,
                              hipStream_t stream)
{
  const float* x      = (const float*)d_in[0];
  const float* ln1_w  = (const float*)d_in[1];
  const float* ln1_b  = (const float*)d_in[2];
  const float* qkv_w  = (const float*)d_in[3];
  const float* qkv_b  = (const float*)d_in[4];
  const float* proj_w = (const float*)d_in[5];
  const float* proj_b = (const float*)d_in[6];
  const float* ln2_w  = (const float*)d_in[7];
  const float* ln2_b  = (const float*)d_in[8];
  const float* fc1_w  = (const float*)d_in[9];
  const float* fc1_b  = (const float*)d_in[10];
  const float* fc2_w  = (const float*)d_in[11];
  const float* fc2_b  = (const float*)d_in[12];

  char* base = (char*)d_ws;
  size_t off = 0;
  auto take = [&](size_t bytes) {
    void* r = base + off;
    off = (off + bytes + 255) & ~(size_t)255;
    return r;
  };
  unsigned short* wq = (unsigned short*)take(2304ull * 768 * 2);
  unsigned short* wp = (unsigned short*)take(768ull * 768 * 2);
  unsigned short* w1 = (unsigned short*)take(3072ull * 768 * 2);
  unsigned short* w2 = (unsigned short*)take(768ull * 3072 * 2);
  unsigned short* h  = (unsigned short*)take(4096ull * 768 * 2);   // LN out / attn O / LN2 out
  float* x2          = (float*)take(4096ull * 768 * 4);            // post-attn residual stream
  char* big          = (char*)take(4096ull * 3072 * 2);            // Q,K,V then FC1 act
  unsigned short* Qb = (unsigned short*)big;
  unsigned short* Kb = (unsigned short*)(big + 4096ull * 768 * 2);
  unsigned short* Vb = (unsigned short*)(big + 2ull * 4096 * 768 * 2);  // frag-major
  unsigned short* a2 = (unsigned short*)big;
  float* part        = (float*)take(4ull * 4096 * 768 * 4);        // split-K partials (50.3 MB)
  const bool can_split = off <= ws_size;

  int n4;
  n4 = 2304 * 768 / 4; cvt_bf16<<<(n4 + 255) / 256, 256, 0, stream>>>(qkv_w, wq, n4);
  n4 = 768 * 768 / 4;  cvt_bf16<<<(n4 + 255) / 256, 256, 0, stream>>>(proj_w, wp, n4);
  n4 = 3072 * 768 / 4; cvt_bf16<<<(n4 + 255) / 256, 256, 0, stream>>>(fc1_w, w1, n4);
  n4 = 768 * 3072 / 4; cvt_bf16<<<(n4 + 255) / 256, 256, 0, stream>>>(fc2_w, w2, n4);

  ln_kernel<<<4096, 256, 0, stream>>>(x, ln1_w, ln1_b, h);
  gemm_nt<0><<<dim3(18, 32), 256, 0, stream>>>(h, wq, qkv_b, nullptr, Qb, Kb, Vb, 4096, 2304, 768, 768);
  attn_fwd<<<dim3(32, 24), 256, 0, stream>>>(Qb, Kb, Vb, h);

  if (can_split) {
    gemm_nt<4><<<dim3(6, 32, 2), 256, 0, stream>>>(h, wp, nullptr, nullptr, part, nullptr, nullptr, 4096, 768, 384, 768);
    reduce_k<2><<<3072, 256, 0, stream>>>(part, proj_b, x, x2);
  } else {
    gemm_nt<1><<<dim3(6, 32), 256, 0, stream>>>(h, wp, proj_b, x, x2, nullptr, nullptr, 4096, 768, 768, 768);
  }

  ln_kernel<<<4096, 256, 0, stream>>>(x2, ln2_w, ln2_b, h);
  gemm_nt<2><<<dim3(24, 32), 256, 0, stream>>>(h, w1, fc1_b, nullptr, a2, nullptr, nullptr, 4096, 3072, 768, 768);

  if (can_split) {
    gemm_nt<4><<<dim3(6, 32, 4), 256, 0, stream>>>(a2, w2, nullptr, nullptr, part, nullptr, nullptr, 4096, 768, 768, 3072);
    reduce_k<4><<<3072, 256, 0, stream>>>(part, fc2_b, x2, (float*)d_out);
  } else {
    gemm_nt<3><<<dim3(6, 32), 256, 0, stream>>>(a2, w2, fc2_b, x2, d_out, nullptr, nullptr, 4096, 768, 3072, 3072);
  }
}

// Round 10
// 194.741 us; speedup vs baseline: 1.2549x; 1.0628x over previous
//
#include <hip/hip_runtime.h>
#include <hip/hip_bf16.h>

typedef __attribute__((ext_vector_type(8))) short short8;
typedef __attribute__((ext_vector_type(4))) float f32x4;
typedef __attribute__((ext_vector_type(4))) int i32x4;

// float -> bf16 bits, round-to-nearest-even
__device__ inline unsigned short f2bs(float f) {
  union { float f; unsigned u; } v; v.f = f;
  unsigned r = v.u + 0x7fff + ((v.u >> 16) & 1);
  return (unsigned short)(r >> 16);
}

__device__ inline unsigned pkbf(float a, float b) {
  __hip_bfloat162 h = __float22bfloat162_rn(float2{a, b});
  union { __hip_bfloat162 h; unsigned u; } c; c.h = h;
  return c.u;
}

__device__ inline float exp2v(float x) {  // 2^x via v_exp_f32 (1 VALU op)
  float r; asm("v_exp_f32 %0, %1" : "=v"(r) : "v"(x)); return r;
}

__device__ inline float max3f(float a, float b, float c) {
  return fmaxf(fmaxf(a, b), c);   // fuses to v_max3_f32
}

__device__ inline void gload16(const void* g, void* l) {
  __builtin_amdgcn_global_load_lds((const __attribute__((address_space(1))) void*)g,
                                   (__attribute__((address_space(3))) void*)l,
                                   16, 0, 0);
}

// ---------------- all weights fp32 -> bf16 in one launch ----------------
__global__ __launch_bounds__(256)
void cvt_all(const float* __restrict__ s0, const float* __restrict__ s1,
             const float* __restrict__ s2, const float* __restrict__ s3,
             unsigned short* __restrict__ d0, unsigned short* __restrict__ d1,
             unsigned short* __restrict__ d2, unsigned short* __restrict__ d3)
{
  // float4 segment sizes: qkv 442368, proj 147456, fc1 589824, fc2 589824
  size_t i = (size_t)blockIdx.x * 256 + threadIdx.x;
  const float* src; unsigned short* dst;
  if (i < 442368) { src = s0; dst = d0; }
  else if (i < 589824) { src = s1; dst = d1; i -= 442368; }
  else if (i < 1179648) { src = s2; dst = d2; i -= 589824; }
  else { src = s3; dst = d3; i -= 1179648; }
  float4 v = ((const float4*)src)[i];
  ushort4 o;
  o.x = f2bs(v.x); o.y = f2bs(v.y); o.z = f2bs(v.z); o.w = f2bs(v.w);
  ((ushort4*)dst)[i] = o;
}

// ---------------- LayerNorm: fp32 in -> bf16 out ----------------
__global__ __launch_bounds__(256)
void ln_kernel(const float* __restrict__ x, const float* __restrict__ w,
               const float* __restrict__ bsh, unsigned short* __restrict__ out)
{
  const int row = blockIdx.x;
  const float* xr = x + (size_t)row * 768;
  float v[3];
  float s = 0.f, sq = 0.f;
#pragma unroll
  for (int i = 0; i < 3; ++i) {
    v[i] = xr[threadIdx.x + i * 256];
    s += v[i]; sq += v[i] * v[i];
  }
#pragma unroll
  for (int d = 1; d < 64; d <<= 1) {
    s  += __shfl_xor(s, d, 64);
    sq += __shfl_xor(sq, d, 64);
  }
  __shared__ float ss[4], ssq[4];
  const int wv = threadIdx.x >> 6;
  if ((threadIdx.x & 63) == 0) { ss[wv] = s; ssq[wv] = sq; }
  __syncthreads();
  s  = ss[0] + ss[1] + ss[2] + ss[3];
  sq = ssq[0] + ssq[1] + ssq[2] + ssq[3];
  const float mu = s * (1.0f / 768.0f);
  const float var = sq * (1.0f / 768.0f) - mu * mu;
  const float rstd = rsqrtf(var + 1e-5f);
#pragma unroll
  for (int i = 0; i < 3; ++i) {
    const int c = threadIdx.x + i * 256;
    out[(size_t)row * 768 + c] = f2bs((v[i] - mu) * rstd * w[c] + bsh[c]);
  }
}

// ---------------- proj reduce + residual + LN2 fused ----------------
// x2 = p0 + p1 + proj_b + x;  h = LN(x2, ln2_w, ln2_b) bf16
__global__ __launch_bounds__(256)
void reduce_ln2(const float* __restrict__ p, const float* __restrict__ bias,
                const float* __restrict__ resid, const float* __restrict__ lw,
                const float* __restrict__ lb, float* __restrict__ x2,
                unsigned short* __restrict__ h)
{
  const size_t MN = 4096ull * 768;
  const int row = blockIdx.x;
  const size_t r0 = (size_t)row * 768;
  float v[3];
  float s = 0.f, sq = 0.f;
#pragma unroll
  for (int i = 0; i < 3; ++i) {
    const int c = threadIdx.x + i * 256;
    const float a = p[r0 + c] + p[MN + r0 + c] + bias[c] + resid[r0 + c];
    x2[r0 + c] = a;
    v[i] = a; s += a; sq += a * a;
  }
#pragma unroll
  for (int d = 1; d < 64; d <<= 1) {
    s  += __shfl_xor(s, d, 64);
    sq += __shfl_xor(sq, d, 64);
  }
  __shared__ float ss[4], ssq[4];
  const int wv = threadIdx.x >> 6;
  if ((threadIdx.x & 63) == 0) { ss[wv] = s; ssq[wv] = sq; }
  __syncthreads();
  s  = ss[0] + ss[1] + ss[2] + ss[3];
  sq = ssq[0] + ssq[1] + ssq[2] + ssq[3];
  const float mu = s * (1.0f / 768.0f);
  const float var = sq * (1.0f / 768.0f) - mu * mu;
  const float rstd = rsqrtf(var + 1e-5f);
#pragma unroll
  for (int i = 0; i < 3; ++i) {
    const int c = threadIdx.x + i * 256;
    h[r0 + c] = f2bs((v[i] - mu) * rstd * lw[c] + lb[c]);
  }
}

// ---------------- split-K reduce: out = sum_s p[s] + bias + resid ----------------
template<int S>
__global__ __launch_bounds__(256)
void reduce_k(const float* __restrict__ p, const float* __restrict__ bias,
              const float* __restrict__ resid, float* __restrict__ out)
{
  const size_t MN = 4096ull * 768;
  const size_t i = ((size_t)blockIdx.x * 256 + threadIdx.x) * 4;
  float4 a = *(const float4*)(p + i);
#pragma unroll
  for (int s = 1; s < S; ++s) {
    float4 b = *(const float4*)(p + s * MN + i);
    a.x += b.x; a.y += b.y; a.z += b.z; a.w += b.w;
  }
  const int col = (int)(i % 768);
  float4 bb = *(const float4*)(bias + col);
  float4 rr = *(const float4*)(resid + i);
  a.x += bb.x + rr.x; a.y += bb.y + rr.y; a.z += bb.z + rr.z; a.w += bb.w + rr.w;
  *(float4*)(out + i) = a;
}

// ---------------- NT GEMM: C[m,n] = sum_k A[m,k]*Bw[n,k], bf16 in, f32 acc ----------------
// XCD-swizzled blockIdx, 3-buffer LDS, single barrier/K-step, counted vmcnt.
// EPI 0: qkv scatter -> Q (pre-scaled by 8*log2e), K bf16 [B,H,N,D]; V frag-major
// EPI 1/3: + bias + resid -> f32 out;  EPI 2: + bias, GELU(tanh) -> bf16;  EPI 4: raw partial
template<int EPI>
__global__ __launch_bounds__(256, 3)
void gemm_nt(const unsigned short* __restrict__ A,
             const unsigned short* __restrict__ Bw,
             const float* __restrict__ bias,
             const float* __restrict__ resid,
             void* __restrict__ out0, void* __restrict__ out1, void* __restrict__ out2,
             int M, int N, int Kslice, int Kstride)
{
  __shared__ __align__(16) unsigned short As[3][128 * 32];
  __shared__ __align__(16) unsigned short Bs[3][128 * 32];
  const int tid = threadIdx.x;
  const int lane = tid & 63;
  const int w = tid >> 6;
  const int wr = w >> 1, wc = w & 1;
  const int l15 = lane & 15, g = lane >> 4;

  const int nwg = gridDim.x * gridDim.y;
  const int hw = blockIdx.y * gridDim.x + blockIdx.x;
  const int virt = (hw & 7) * (nwg >> 3) + (hw >> 3);
  const int m0 = (virt / gridDim.x) * 128;
  const int n0 = (virt % gridDim.x) * 128;
  const int kbase = blockIdx.z * Kslice;

  f32x4 acc[4][4];
#pragma unroll
  for (int m = 0; m < 4; ++m)
#pragma unroll
    for (int n = 0; n < 4; ++n)
      acc[m][n] = (f32x4){0.f, 0.f, 0.f, 0.f};

  auto stage = [&](int buf, int k0) {
#pragma unroll
    for (int i = 0; i < 2; ++i) {
      const int f = tid + i * 256;
      const int row = f >> 2, c8 = f & 3;
      const int sc = c8 ^ (row & 3);
      gload16(A  + (size_t)(m0 + row) * Kstride + kbase + k0 + sc * 8, (char*)&As[buf][0] + f * 16);
      gload16(Bw + (size_t)(n0 + row) * Kstride + kbase + k0 + sc * 8, (char*)&Bs[buf][0] + f * 16);
    }
  };

  const int NT = Kslice >> 5;
  stage(0, 0);
  stage(1, 32);

  for (int t = 0; t < NT; ++t) {
    const int buf = t % 3;
    if (t + 1 < NT) {
      asm volatile("s_waitcnt vmcnt(4)" ::: "memory");
    } else {
      asm volatile("s_waitcnt vmcnt(0)" ::: "memory");
    }
    __builtin_amdgcn_s_barrier();
    asm volatile("" ::: "memory");
    if (t + 2 < NT) stage((t + 2) % 3, (t + 2) * 32);

    short8 af[4], bfr[4];
#pragma unroll
    for (int m = 0; m < 4; ++m) {
      const int r = wr * 64 + m * 16 + l15;
      af[m] = *(const short8*)((const char*)&As[buf][0] + ((size_t)r * 32 + (g ^ (r & 3)) * 8) * 2);
    }
#pragma unroll
    for (int n = 0; n < 4; ++n) {
      const int r = wc * 64 + n * 16 + l15;
      bfr[n] = *(const short8*)((const char*)&Bs[buf][0] + ((size_t)r * 32 + (g ^ (r & 3)) * 8) * 2);
    }
#pragma unroll
    for (int m = 0; m < 4; ++m)
#pragma unroll
      for (int n = 0; n < 4; ++n)
        acc[m][n] = __builtin_amdgcn_mfma_f32_16x16x32_bf16(af[m], bfr[n], acc[m][n], 0, 0, 0);
    asm volatile("" ::: "memory");
  }

  // epilogue: C/D layout col = lane&15, row = (lane>>4)*4 + j
#pragma unroll
  for (int m = 0; m < 4; ++m) {
    const int gmBase = m0 + wr * 64 + m * 16 + g * 4;
#pragma unroll
    for (int n = 0; n < 4; ++n) {
      const int gn = n0 + wc * 64 + n * 16 + l15;
      const float bval = (EPI == 4) ? 0.0f : bias[gn];
      float vj[4];
#pragma unroll
      for (int j = 0; j < 4; ++j) vj[j] = acc[m][n][j] + bval;
      if (EPI == 0) {
        const int three = gn / 768;
        const int hh = (gn % 768) >> 6;
        const int d = gn & 63;
        const int bb = gmBase >> 11, t = gmBase & 2047;
        if (three == 2) {
          // V frag-major
          ushort4 pk;
          pk.x = f2bs(vj[0]); pk.y = f2bs(vj[1]); pk.z = f2bs(vj[2]); pk.w = f2bs(vj[3]);
          const int kt = t & 63;
          const size_t pos = ((((size_t)(bb * 12 + hh) * 32 + (t >> 6)) * 8 + (d >> 4) * 2 + (kt >> 5)) * 64
                              + ((kt >> 2) & 3) * 16 + (d & 15)) * 8 + ((kt >> 4) & 1) * 4;
          *(ushort4*)((unsigned short*)out2 + pos) = pk;
        } else {
          unsigned short* dst = (three == 0) ? (unsigned short*)out0 : (unsigned short*)out1;
#pragma unroll
          for (int j = 0; j < 4; ++j) {
            float v = vj[j];
            if (three == 0) v *= 11.5415603f;   // 8 * log2(e): attention in exp2 domain
            dst[(((size_t)bb * 12 + hh) * 2048 + (t + j)) * 64 + d] = f2bs(v);
          }
        }
      } else if (EPI == 1 || EPI == 3) {
#pragma unroll
        for (int j = 0; j < 4; ++j) {
          const int gm = gmBase + j;
          ((float*)out0)[(size_t)gm * N + gn] = vj[j] + resid[(size_t)gm * N + gn];
        }
      } else if (EPI == 2) {
#pragma unroll
        for (int j = 0; j < 4; ++j) {
          const int gm = gmBase + j;
          // GELU exact ~ tanh form: v - v/(1+exp2(k*u)), |err|<3e-3
          const float vv = vj[j];
          const float u = vv * (1.0f + 0.044715f * vv * vv);
          const float E = exp2v(2.0f * 0.7978845608f * 1.4426950409f * u);
          const float ge = vv - vv / (1.0f + E);
          ((unsigned short*)out0)[(size_t)gm * N + gn] = f2bs(ge);
        }
      } else {  // EPI == 4: raw partial
        float* po = (float*)out0 + (size_t)blockIdx.z * M * N;
#pragma unroll
        for (int j = 0; j < 4; ++j) {
          const int gm = gmBase + j;
          po[(size_t)gm * N + gn] = vj[j];
        }
      }
    }
  }
}

// ---------------- Flash attention fwd v8 ----------------
// v7 + T13 defer-max (THR=8 in exp2 domain) + max3 trees.
// Swapped QK^T (lane-local P rows); K frag-ordered LDS; V frag-major global ->
// linear staging -> single conflict-free ds_read_b128 per PV fragment.
// 3-buffer, single barrier per tile, counted vmcnt. exp2-domain softmax.
__global__ __launch_bounds__(256, 3)
void attn_fwd(const unsigned short* __restrict__ Q,
              const unsigned short* __restrict__ K,
              const unsigned short* __restrict__ Vf,
              unsigned short* __restrict__ O)
{
  __shared__ __align__(1024) unsigned short Ks[3][4096];  // frag f=n*2+kc at f*512+lane*8
  __shared__ __align__(1024) unsigned short Vs[3][4096];  // frag-major linear copy of Vf tile
  const int tid = threadIdx.x, lane = tid & 63, w = tid >> 6;
  const int l15 = lane & 15, g = lane >> 4;

  const int hw = blockIdx.y * gridDim.x + blockIdx.x;
  const int virt = (hw & 7) * 96 + (hw >> 3);
  const int qblk = virt & 31;
  const int bh = virt >> 5;
  const int b = bh / 12, h = bh % 12;
  const int q0 = qblk * 64;
  const unsigned short* Qb = Q  + (size_t)bh * 2048 * 64;
  const unsigned short* Kb = K  + (size_t)bh * 2048 * 64;
  const unsigned short* Vb = Vf + (size_t)bh * 2048 * 64;  // frag-major per bh

  const int qr = q0 + w * 16 + l15;
  short8 qf[2];
  qf[0] = *(const short8*)(Qb + (size_t)qr * 64 + g * 8);
  qf[1] = *(const short8*)(Qb + (size_t)qr * 64 + 32 + g * 8);

  float m_run = -1e30f, l_part = 0.f;
  f32x4 o_acc[4];
#pragma unroll
  for (int dc = 0; dc < 4; ++dc) o_acc[dc] = (f32x4){0.f, 0.f, 0.f, 0.f};

  auto stage = [&](int buf, int tIdx) {
    const int kb = tIdx * 64;
#pragma unroll
    for (int i = 0; i < 2; ++i) {
      const int f = w * 2 + i;
      const int n = f >> 1, kc = f & 1;
      gload16(Kb + (size_t)(kb + n * 16 + l15) * 64 + kc * 32 + g * 8,
              (char*)&Ks[buf][0] + f * 1024);
    }
#pragma unroll
    for (int i = 0; i < 2; ++i) {
      const int chunk = tid + i * 256;
      gload16(Vb + (size_t)tIdx * 4096 + chunk * 8,
              (char*)&Vs[buf][0] + chunk * 16);
    }
  };

  stage(0, 0);
  stage(1, 1);

  for (int t = 0; t < 32; ++t) {
    const int buf = t % 3;
    if (t < 31) {
      asm volatile("s_waitcnt vmcnt(4)" ::: "memory");
    } else {
      asm volatile("s_waitcnt vmcnt(0)" ::: "memory");
    }
    __builtin_amdgcn_s_barrier();
    asm volatile("" ::: "memory");
    if (t < 30) stage((t + 2) % 3, t + 2);

    // --- S^T = K · Q^T : lane holds S[q=l15][key = n*16 + 4g + j] (log2 domain) ---
    f32x4 s2[4];
#pragma unroll
    for (int n = 0; n < 4; ++n) s2[n] = (f32x4){0.f, 0.f, 0.f, 0.f};
    __builtin_amdgcn_s_setprio(1);
#pragma unroll
    for (int n = 0; n < 4; ++n) {
      short8 kf0 = *(const short8*)(&Ks[buf][(n * 2 + 0) * 512 + lane * 8]);
      short8 kf1 = *(const short8*)(&Ks[buf][(n * 2 + 1) * 512 + lane * 8]);
      s2[n] = __builtin_amdgcn_mfma_f32_16x16x32_bf16(kf0, qf[0], s2[n], 0, 0, 0);
      s2[n] = __builtin_amdgcn_mfma_f32_16x16x32_bf16(kf1, qf[1], s2[n], 0, 0, 0);
    }
    __builtin_amdgcn_s_setprio(0);

    // --- online softmax (exp2 domain), q = l15 per lane, defer-max THR=8 ---
    float mx = max3f(max3f(s2[0][0], s2[0][1], s2[0][2]),
                     max3f(s2[0][3], s2[1][0], s2[1][1]),
                     max3f(s2[1][2], s2[1][3], s2[2][0]));
    mx = max3f(mx, max3f(s2[2][1], s2[2][2], s2[2][3]),
                   max3f(s2[3][0], s2[3][1], fmaxf(s2[3][2], s2[3][3])));
    mx = fmaxf(mx, __shfl_xor(mx, 16, 64));
    mx = fmaxf(mx, __shfl_xor(mx, 32, 64));
    if (__any(mx > m_run + 8.0f)) {    // T13: rescale only on large max growth
      const float mn = fmaxf(m_run, mx);
      const float alpha = exp2v(m_run - mn);
      m_run = mn;
      l_part *= alpha;
#pragma unroll
      for (int j = 0; j < 4; ++j) {
        const float aB = __shfl(alpha, (lane & 48) | (g * 4 + j), 64);
#pragma unroll
        for (int dc = 0; dc < 4; ++dc) o_acc[dc][j] *= aB;
      }
    }
    float e[4][4];
    float rs = 0.f;
#pragma unroll
    for (int n = 0; n < 4; ++n)
#pragma unroll
      for (int j = 0; j < 4; ++j) {
        e[n][j] = exp2v(s2[n][j] - m_run);   // bounded by 2^8
        rs += e[n][j];
      }
    l_part += rs;   // per-lane partial; cross-lane reduce deferred to epilogue

    // --- pack P fragments: slot i -> key (2kc + (i>=4))*16 + 4g + (i&3) ---
    unsigned pw[2][4];
#pragma unroll
    for (int kc = 0; kc < 2; ++kc) {
      pw[kc][0] = pkbf(e[2 * kc][0],     e[2 * kc][1]);
      pw[kc][1] = pkbf(e[2 * kc][2],     e[2 * kc][3]);
      pw[kc][2] = pkbf(e[2 * kc + 1][0], e[2 * kc + 1][1]);
      pw[kc][3] = pkbf(e[2 * kc + 1][2], e[2 * kc + 1][3]);
    }

    // --- O += P · V : frag-major Vs, one b128 per fragment, conflict-free ---
    const char* vsb = (const char*)&Vs[buf][0];
    __builtin_amdgcn_s_setprio(1);
#pragma unroll
    for (int kc = 0; kc < 2; ++kc) {
      i32x4 pt; pt.x = (int)pw[kc][0]; pt.y = (int)pw[kc][1]; pt.z = (int)pw[kc][2]; pt.w = (int)pw[kc][3];
      short8 pf = *(short8*)&pt;
#pragma unroll
      for (int dc = 0; dc < 4; ++dc) {
        short8 vfr = *(const short8*)(vsb + (((dc * 2 + kc) * 64 + lane) * 16));
        o_acc[dc] = __builtin_amdgcn_mfma_f32_16x16x32_bf16(pf, vfr, o_acc[dc], 0, 0, 0);
      }
    }
    __builtin_amdgcn_s_setprio(0);
    asm volatile("" ::: "memory");
  }

  // --- epilogue: reduce l across lane groups, then write O ---
  l_part += __shfl_xor(l_part, 16, 64);
  l_part += __shfl_xor(l_part, 32, 64);
#pragma unroll
  for (int j = 0; j < 4; ++j) {
    const float lB = __shfl(l_part, (lane & 48) | (g * 4 + j), 64);
    const float inv = 1.0f / lB;
    const int qrow = q0 + w * 16 + g * 4 + j;
#pragma unroll
    for (int dc = 0; dc < 4; ++dc) {
      O[((size_t)b * 2048 + qrow) * 768 + h * 64 + dc * 16 + l15] = f2bs(o_acc[dc][j] * inv);
    }
  }
}

extern "C" void kernel_launch(void* const* d_in, const int* in_sizes, int n_in,
                              void* d_out, int out_size, void* d_ws, size_t ws_size,
                              hipStream_t stream)
{
  const float* x      = (const float*)d_in[0];
  const float* ln1_w  = (const float*)d_in[1];
  const float* ln1_b  = (const float*)d_in[2];
  const float* qkv_w  = (const float*)d_in[3];
  const float* qkv_b  = (const float*)d_in[4];
  const float* proj_w = (const float*)d_in[5];
  const float* proj_b = (const float*)d_in[6];
  const float* ln2_w  = (const float*)d_in[7];
  const float* ln2_b  = (const float*)d_in[8];
  const float* fc1_w  = (const float*)d_in[9];
  const float* fc1_b  = (const float*)d_in[10];
  const float* fc2_w  = (const float*)d_in[11];
  const float* fc2_b  = (const float*)d_in[12];

  char* base = (char*)d_ws;
  size_t off = 0;
  auto take = [&](size_t bytes) {
    void* r = base + off;
    off = (off + bytes + 255) & ~(size_t)255;
    return r;
  };
  unsigned short* wq = (unsigned short*)take(2304ull * 768 * 2);
  unsigned short* wp = (unsigned short*)take(768ull * 768 * 2);
  unsigned short* w1 = (unsigned short*)take(3072ull * 768 * 2);
  unsigned short* w2 = (unsigned short*)take(768ull * 3072 * 2);
  unsigned short* h  = (unsigned short*)take(4096ull * 768 * 2);   // LN out / attn O / LN2 out
  float* x2          = (float*)take(4096ull * 768 * 4);            // post-attn residual stream
  char* big          = (char*)take(4096ull * 3072 * 2);            // Q,K,V then FC1 act
  unsigned short* Qb = (unsigned short*)big;
  unsigned short* Kb = (unsigned short*)(big + 4096ull * 768 * 2);
  unsigned short* Vb = (unsigned short*)(big + 2ull * 4096 * 768 * 2);  // frag-major
  unsigned short* a2 = (unsigned short*)big;
  float* part        = (float*)take(4ull * 4096 * 768 * 4);        // split-K partials (50.3 MB)
  const bool can_split = off <= ws_size;

  cvt_all<<<6912, 256, 0, stream>>>(qkv_w, proj_w, fc1_w, fc2_w, wq, wp, w1, w2);

  ln_kernel<<<4096, 256, 0, stream>>>(x, ln1_w, ln1_b, h);
  gemm_nt<0><<<dim3(18, 32), 256, 0, stream>>>(h, wq, qkv_b, nullptr, Qb, Kb, Vb, 4096, 2304, 768, 768);
  attn_fwd<<<dim3(32, 24), 256, 0, stream>>>(Qb, Kb, Vb, h);

  if (can_split) {
    gemm_nt<4><<<dim3(6, 32, 2), 256, 0, stream>>>(h, wp, nullptr, nullptr, part, nullptr, nullptr, 4096, 768, 384, 768);
    reduce_ln2<<<4096, 256, 0, stream>>>(part, proj_b, x, ln2_w, ln2_b, x2, h);
  } else {
    gemm_nt<1><<<dim3(6, 32), 256, 0, stream>>>(h, wp, proj_b, x, x2, nullptr, nullptr, 4096, 768, 768, 768);
    ln_kernel<<<4096, 256, 0, stream>>>(x2, ln2_w, ln2_b, h);
  }

  gemm_nt<2><<<dim3(24, 32), 256, 0, stream>>>(h, w1, fc1_b, nullptr, a2, nullptr, nullptr, 4096, 3072, 768, 768);

  if (can_split) {
    gemm_nt<4><<<dim3(6, 32, 4), 256, 0, stream>>>(a2, w2, nullptr, nullptr, part, nullptr, nullptr, 4096, 768, 768, 3072);
    reduce_k<4><<<3072, 256, 0, stream>>>(part, fc2_b, x2, (float*)d_out);
  } else {
    gemm_nt<3><<<dim3(6, 32), 256, 0, stream>>>(a2, w2, fc2_b, x2, d_out, nullptr, nullptr, 4096, 768, 3072, 3072);
  }
}